// Round 1
// baseline (957.742 us; speedup 1.0000x reference)
//
#include <hip/hip_runtime.h>
#include <hip/hip_bf16.h>

#define N_NODES 50000
#define N_EDGES 1600000
#define NGRAPH  16
#define HID     128

// ---------------- zero init (ws is poisoned 0xAA every call) ----------------
__global__ __launch_bounds__(256) void k_zero(float* p, int n) {
    int i = blockIdx.x * 256 + threadIdx.x;
    if (i < n) p[i] = 0.f;
}

// ---------------- degree histogram + per-node edge_attr sum ----------------
__global__ __launch_bounds__(256) void k_deg_ea(const int* __restrict__ row,
                                                const float* __restrict__ ea,
                                                int* __restrict__ counts,
                                                float* __restrict__ ea_sum) {
    int e = blockIdx.x * 256 + threadIdx.x;
    if (e < N_EDGES) {
        int r = row[e];
        atomicAdd(&counts[r], 1);
        atomicAdd(&ea_sum[r], ea[e]);
    }
}

// ---------------- single-block exclusive scan over counts[N] ----------------
__global__ __launch_bounds__(1024) void k_scan(const int* __restrict__ counts,
                                               int* __restrict__ offs,
                                               int* __restrict__ cursor) {
    const int T = 1024;
    const int CHUNK = (N_NODES + T - 1) / T; // 49
    __shared__ int sums[T];
    int t = threadIdx.x;
    int base = t * CHUNK;
    int s = 0;
    for (int i = 0; i < CHUNK; i++) {
        int idx = base + i;
        if (idx < N_NODES) s += counts[idx];
    }
    sums[t] = s;
    __syncthreads();
    // Hillis-Steele inclusive scan
    for (int d = 1; d < T; d <<= 1) {
        int v = (t >= d) ? sums[t - d] : 0;
        __syncthreads();
        sums[t] += v;
        __syncthreads();
    }
    int excl = sums[t] - s;
    for (int i = 0; i < CHUNK; i++) {
        int idx = base + i;
        if (idx < N_NODES) {
            offs[idx] = excl;
            cursor[idx] = excl;
            excl += counts[idx];
        }
    }
    if (t == T - 1) offs[N_NODES] = excl; // == E
}

// ---------------- scatter edges into CSR (by row) ----------------
__global__ __launch_bounds__(256) void k_scatter(const int* __restrict__ row,
                                                 const int* __restrict__ col,
                                                 int* __restrict__ cursor,
                                                 int* __restrict__ csr_col) {
    int e = blockIdx.x * 256 + threadIdx.x;
    if (e < N_EDGES) {
        int r = row[e];
        int slot = atomicAdd(&cursor[r], 1);
        csr_col[slot] = col[e];
    }
}

// ------- precompute: transpose W2 (3 layers) + W7; v3[l] = W3[l] @ relu(W4[l]) -------
__global__ __launch_bounds__(256) void k_prep(const float* __restrict__ W2,
                                              const float* __restrict__ W7,
                                              const float* __restrict__ W3,
                                              const float* __restrict__ W4,
                                              float* __restrict__ w2t,
                                              float* __restrict__ w7t,
                                              float* __restrict__ v3) {
    int idx = blockIdx.x * 256 + threadIdx.x;
    if (idx < 4 * HID * HID) {
        int m = idx / (HID * HID), r = idx % (HID * HID);
        int hp = r / HID, h = r % HID; // source [hp][h]
        const float* src = (m < 3) ? (W2 + m * HID * HID) : W7;
        float*       dst = (m < 3) ? (w2t + m * HID * HID) : w7t;
        dst[h * HID + hp] = src[hp * HID + h];
    }
    if (idx < 3 * HID) {
        int l = idx / HID, hp = idx % HID;
        float acc = 0.f;
        for (int h = 0; h < HID; h++)
            acc += W3[l * HID * HID + hp * HID + h] * fmaxf(W4[l * HID + h], 0.f);
        v3[idx] = acc;
    }
}

// ---------------- hop 0: emb = relu(x*w1 + ea_sum*v3) ----------------
__global__ __launch_bounds__(256) void k_hop0(const float* __restrict__ x,
                                              const float* __restrict__ ea_sum,
                                              const float* __restrict__ w1,
                                              const float* __restrict__ v3,
                                              float* __restrict__ emb) {
    int idx = blockIdx.x * 256 + threadIdx.x;
    if (idx < N_NODES * HID) {
        int n = idx >> 7, h = idx & 127;
        emb[idx] = fmaxf(x[n] * w1[h] + ea_sum[n] * v3[h], 0.f);
    }
}

// ---------------- gather: agg[n] = sum over neighbors col of emb[col] ----------------
// one wave per node; lane holds an h-pair (float2)
__global__ __launch_bounds__(256) void k_gather(const float* __restrict__ emb,
                                                const int* __restrict__ offs,
                                                const int* __restrict__ csr,
                                                float* __restrict__ agg) {
    int wave = (blockIdx.x * 256 + threadIdx.x) >> 6;
    int lane = threadIdx.x & 63;
    if (wave >= N_NODES) return;
    int s = offs[wave], e = offs[wave + 1];
    const float2* eb = (const float2*)emb;
    float2 a0 = {0.f, 0.f}, a1 = {0.f, 0.f};
    int j = s;
    for (; j + 2 <= e; j += 2) {
        int c0 = csr[j], c1 = csr[j + 1];
        float2 v0 = eb[(size_t)c0 * 64 + lane];
        float2 v1 = eb[(size_t)c1 * 64 + lane];
        a0.x += v0.x; a0.y += v0.y;
        a1.x += v1.x; a1.y += v1.y;
    }
    if (j < e) {
        int c = csr[j];
        float2 v = eb[(size_t)c * 64 + lane];
        a0.x += v.x; a0.y += v.y;
    }
    float2 r; r.x = a0.x + a1.x; r.y = a0.y + a1.y;
    ((float2*)agg)[(size_t)wave * 64 + lane] = r;
}

// --------- in-place GEMM + fuse: buf[n] = relu(buf[n]@W2T + x[n]*w1 + ea_sum[n]*v3) ---------
// 64-node tile in LDS; wave w owns 16 nodes, lane owns h'-pair 2*lane
__global__ __launch_bounds__(256) void k_gemm_relu(float* __restrict__ buf,
                                                   const float* __restrict__ w2tl,
                                                   const float* __restrict__ w1l,
                                                   const float* __restrict__ v3l,
                                                   const float* __restrict__ x,
                                                   const float* __restrict__ ea_sum) {
    __shared__ float tile[64 * HID]; // 32 KB
    int tid = threadIdx.x;
    int tbase = blockIdx.x * 64;
    const float4* src = (const float4*)(buf + (size_t)tbase * HID);
    float4* dst4 = (float4*)tile;
    int vn = N_NODES - tbase; if (vn > 64) vn = 64;
    int lim = vn * (HID / 4);
    for (int i = tid; i < 64 * HID / 4; i += 256) {
        float4 v = (i < lim) ? src[i] : float4{0.f, 0.f, 0.f, 0.f};
        dst4[i] = v;
    }
    __syncthreads();
    int w = tid >> 6, lane = tid & 63;
    float2 acc[16];
#pragma unroll
    for (int m = 0; m < 16; m++) acc[m] = {0.f, 0.f};
    const float2* w2 = (const float2*)w2tl; // row h at w2[h*64 + lane]
#pragma unroll 2
    for (int h = 0; h < HID; h += 2) {
        float2 w0 = w2[h * 64 + lane];
        float2 w1 = w2[(h + 1) * 64 + lane];
        const float* trow = tile + (w * 16) * HID + h;
#pragma unroll
        for (int m = 0; m < 16; m++) {
            float2 a = *(const float2*)(trow + m * HID); // LDS broadcast
            acc[m].x += a.x * w0.x + a.y * w1.x;
            acc[m].y += a.x * w0.y + a.y * w1.y;
        }
    }
    float2 w1p = ((const float2*)w1l)[lane];
    float2 v3p = ((const float2*)v3l)[lane];
#pragma unroll
    for (int m = 0; m < 16; m++) {
        int n = tbase + w * 16 + m;
        if (n < N_NODES) {
            float xs = x[n], es = ea_sum[n];
            float2 r;
            r.x = fmaxf(acc[m].x + xs * w1p.x + es * v3p.x, 0.f);
            r.y = fmaxf(acc[m].y + xs * w1p.y + es * v3p.y, 0.f);
            ((float2*)buf)[(size_t)n * 64 + lane] = r;
        }
    }
}

// ---------------- graph pooling (batch is sorted; per-block run-length accumulate) ----------------
__global__ __launch_bounds__(128) void k_pool(const float* __restrict__ emb,
                                              const int* __restrict__ batch,
                                              float* __restrict__ pooled) {
    const int CH = 256;
    int t = threadIdx.x;
    int start = blockIdx.x * CH;
    int end = start + CH; if (end > N_NODES) end = N_NODES;
    if (start >= N_NODES) return;
    float acc = 0.f;
    int cur = batch[start];
    for (int n = start; n < end; n++) {
        int g = batch[n];
        if (g != cur) { atomicAdd(&pooled[cur * HID + t], acc); acc = 0.f; cur = g; }
        acc += emb[(size_t)n * HID + t];
    }
    atomicAdd(&pooled[cur * HID + t], acc);
}

// ---------------- per-graph scalar: s_g = relu(pooled@W6T) . W5[:128] ----------------
__global__ __launch_bounds__(128) void k_graph(const float* __restrict__ pooled,
                                               const float* __restrict__ W6,
                                               const float* __restrict__ W5,
                                               float* __restrict__ s_g) {
    int g = blockIdx.x, hp = threadIdx.x;
    float acc = 0.f;
    for (int h = 0; h < HID; h++) acc += pooled[g * HID + h] * W6[hp * HID + h];
    float v = fmaxf(acc, 0.f) * W5[hp];
    __shared__ float red[HID];
    red[hp] = v;
    __syncthreads();
    for (int d = 64; d > 0; d >>= 1) {
        if (hp < d) red[hp] += red[hp + d];
        __syncthreads();
    }
    if (hp == 0) s_g[g] = red[0];
}

// ---------------- final: out[n] = s_{batch[n]} + relu(emb@W7T) . W5[128:] + b5 ----------------
__global__ __launch_bounds__(256) void k_final(const float* __restrict__ emb,
                                               const float* __restrict__ w7t,
                                               const float* __restrict__ W5,
                                               const float* __restrict__ b5,
                                               const int* __restrict__ batch,
                                               const float* __restrict__ s_g,
                                               float* __restrict__ out) {
    __shared__ float tile[64 * HID];
    int tid = threadIdx.x;
    int tbase = blockIdx.x * 64;
    const float4* src = (const float4*)(emb + (size_t)tbase * HID);
    float4* dst4 = (float4*)tile;
    int vn = N_NODES - tbase; if (vn > 64) vn = 64;
    int lim = vn * (HID / 4);
    for (int i = tid; i < 64 * HID / 4; i += 256) {
        float4 v = (i < lim) ? src[i] : float4{0.f, 0.f, 0.f, 0.f};
        dst4[i] = v;
    }
    __syncthreads();
    int w = tid >> 6, lane = tid & 63;
    float2 acc[16];
#pragma unroll
    for (int m = 0; m < 16; m++) acc[m] = {0.f, 0.f};
    const float2* w7 = (const float2*)w7t;
#pragma unroll 2
    for (int h = 0; h < HID; h += 2) {
        float2 w0 = w7[h * 64 + lane];
        float2 w1 = w7[(h + 1) * 64 + lane];
        const float* trow = tile + (w * 16) * HID + h;
#pragma unroll
        for (int m = 0; m < 16; m++) {
            float2 a = *(const float2*)(trow + m * HID);
            acc[m].x += a.x * w0.x + a.y * w1.x;
            acc[m].y += a.x * w0.y + a.y * w1.y;
        }
    }
    float2 w5p = ((const float2*)W5)[64 + lane]; // W5[128+2*lane], W5[129+2*lane]
    float bias = b5[0];
#pragma unroll
    for (int m = 0; m < 16; m++) {
        float p = fmaxf(acc[m].x, 0.f) * w5p.x + fmaxf(acc[m].y, 0.f) * w5p.y;
        // wave-wide sum (64 lanes)
        for (int off = 32; off > 0; off >>= 1) p += __shfl_down(p, off);
        int n = tbase + w * 16 + m;
        if (lane == 0 && n < N_NODES) out[n] = p + s_g[batch[n]] + bias;
    }
}

extern "C" void kernel_launch(void* const* d_in, const int* in_sizes, int n_in,
                              void* d_out, int out_size, void* d_ws, size_t ws_size,
                              hipStream_t stream) {
    (void)in_sizes; (void)n_in; (void)out_size; (void)ws_size;
    const float* x    = (const float*)d_in[0];
    const int*   ei   = (const int*)d_in[1];   // [2,E] flat: row then col
    const float* ea   = (const float*)d_in[2];
    const int*   bat  = (const int*)d_in[3];
    const float* W1   = (const float*)d_in[4]; // [3,128,1]
    const float* W2   = (const float*)d_in[5]; // [3,128,128]
    const float* W3   = (const float*)d_in[6];
    const float* W4   = (const float*)d_in[7]; // [3,128,1]
    const float* W5   = (const float*)d_in[8]; // [1,256]
    const float* b5   = (const float*)d_in[9];
    const float* W6   = (const float*)d_in[10];
    const float* W7   = (const float*)d_in[11];
    float* out = (float*)d_out;

    const int* row = ei;
    const int* col = ei + N_EDGES;

    // workspace layout (all offsets in 4B elems, 16B-aligned)
    float* wsf = (float*)d_ws;
    int*   wsi = (int*)d_ws;
    size_t o = 0;
    int*   counts = wsi + o; o += N_NODES;          // zeroed
    float* ea_sum = wsf + o; o += N_NODES;          // zeroed
    float* pooled = wsf + o; o += NGRAPH * HID;     // zeroed
    float* s_g    = wsf + o; o += NGRAPH;           // zeroed
    size_t ztot = o;                                 // 102064
    int*   offs   = wsi + o; o += N_NODES + 1; o = (o + 3) & ~(size_t)3;
    int*   cursor = wsi + o; o += N_NODES;
    float* v3     = wsf + o; o += 3 * HID;
    float* w2t    = wsf + o; o += 3 * HID * HID;
    float* w7t    = wsf + o; o += HID * HID;
    int*   csr    = wsi + o; o += N_EDGES;
    float* embA   = wsf + o; o += (size_t)N_NODES * HID;
    float* embB   = wsf + o; o += (size_t)N_NODES * HID;

    // 0) zero the accumulator region
    k_zero<<<(int)((ztot + 255) / 256), 256, 0, stream>>>((float*)d_ws, (int)ztot);
    // 1) degree + edge_attr sums
    k_deg_ea<<<(N_EDGES + 255) / 256, 256, 0, stream>>>(row, ea, counts, ea_sum);
    // 2) exclusive scan -> CSR offsets (+ cursor copy)
    k_scan<<<1, 1024, 0, stream>>>(counts, offs, cursor);
    // 3) scatter cols into CSR order
    k_scatter<<<(N_EDGES + 255) / 256, 256, 0, stream>>>(row, col, cursor, csr);
    // 4) weight precompute: W2T (x3), W7T, v3
    k_prep<<<(4 * HID * HID + 255) / 256, 256, 0, stream>>>(W2, W7, W3, W4, w2t, w7t, v3);
    // 5) hop 0 (elementwise) -> embA
    k_hop0<<<(N_NODES * HID + 255) / 256, 256, 0, stream>>>(x, ea_sum, W1, v3, embA);
    // 6) hop 1: gather embA->embB, GEMM in-place on embB
    k_gather<<<(N_NODES * 64) / 256, 256, 0, stream>>>(embA, offs, csr, embB);
    k_gemm_relu<<<(N_NODES + 63) / 64, 256, 0, stream>>>(embB, w2t + 1 * HID * HID,
                                                         W1 + 1 * HID, v3 + 1 * HID, x, ea_sum);
    // 7) hop 2: gather embB->embA, GEMM in-place on embA
    k_gather<<<(N_NODES * 64) / 256, 256, 0, stream>>>(embB, offs, csr, embA);
    k_gemm_relu<<<(N_NODES + 63) / 64, 256, 0, stream>>>(embA, w2t + 2 * HID * HID,
                                                         W1 + 2 * HID, v3 + 2 * HID, x, ea_sum);
    // 8) graph pooling
    k_pool<<<(N_NODES + 255) / 256, 128, 0, stream>>>(embA, bat, pooled);
    // 9) per-graph scalars
    k_graph<<<NGRAPH, 128, 0, stream>>>(pooled, W6, W5, s_g);
    // 10) final head
    k_final<<<(N_NODES + 63) / 64, 256, 0, stream>>>(embA, w7t, W5, b5, bat, s_g, out);
}

// Round 2
// 737.720 us; speedup vs baseline: 1.2982x; 1.2982x over previous
//
#include <hip/hip_runtime.h>
#include <hip/hip_bf16.h>

#define N_NODES 50000
#define N_EDGES 1600000
#define NGRAPH  16
#define HID     128

#define RPB   128                         // rows per bucket
#define NB    ((N_NODES + RPB - 1) / RPB) // 391 buckets
#define NBLK  64                          // partition blocks
#define EPB   ((N_EDGES + NBLK - 1) / NBLK) // 25000 edges per partition block

// ---------------- zero init (ws is poisoned 0xAA every call) ----------------
__global__ __launch_bounds__(256) void k_zero(float* p, int n) {
    int i = blockIdx.x * 256 + threadIdx.x;
    if (i < n) p[i] = 0.f;
}

// ---------------- P1: per-(bucket,block) histogram (LDS atomics only) ----------------
__global__ __launch_bounds__(256) void k_p1_hist(const int* __restrict__ row,
                                                 int* __restrict__ blkhist) {
    __shared__ int hist[NB];
    int tid = threadIdx.x, blk = blockIdx.x;
    for (int i = tid; i < NB; i += 256) hist[i] = 0;
    __syncthreads();
    int s = blk * EPB, e = s + EPB; if (e > N_EDGES) e = N_EDGES;
    for (int i = s + tid; i < e; i += 256)
        atomicAdd(&hist[row[i] >> 7], 1);
    __syncthreads();
    for (int i = tid; i < NB; i += 256)
        blkhist[i * NBLK + blk] = hist[i];
}

// ---------------- P2: bucket bases + per-(bucket,block) cursors (one block) ----------------
__global__ __launch_bounds__(512) void k_p2_scan(int* __restrict__ blkhist,
                                                 int* __restrict__ bucket_base) {
    __shared__ int sums[512];
    int t = threadIdx.x;
    int s = 0;
    if (t < NB)
        for (int k = 0; k < NBLK; k++) s += blkhist[t * NBLK + k];
    sums[t] = s;
    __syncthreads();
    for (int d = 1; d < 512; d <<= 1) {
        int v = (t >= d) ? sums[t - d] : 0;
        __syncthreads();
        sums[t] += v;
        __syncthreads();
    }
    if (t < NB) {
        int excl = sums[t] - s;
        bucket_base[t] = excl;
        int run = excl;
        for (int k = 0; k < NBLK; k++) {
            int tmp = blkhist[t * NBLK + k];
            blkhist[t * NBLK + k] = run;   // becomes per-(bucket,block) base
            run += tmp;
        }
        if (t == NB - 1) bucket_base[NB] = run; // == E
    }
}

// ---------------- P3: scatter packed {row,col,ea} into bucket runs ----------------
__global__ __launch_bounds__(256) void k_p3_part(const int* __restrict__ row,
                                                 const int* __restrict__ col,
                                                 const float* __restrict__ ea,
                                                 const int* __restrict__ blkbase,
                                                 int4* __restrict__ packed) {
    __shared__ int cur[NB];
    int tid = threadIdx.x, blk = blockIdx.x;
    for (int i = tid; i < NB; i += 256) cur[i] = blkbase[i * NBLK + blk];
    __syncthreads();
    int s = blk * EPB, e = s + EPB; if (e > N_EDGES) e = N_EDGES;
    for (int i = s + tid; i < e; i += 256) {
        int r = row[i], c = col[i];
        float a = ea[i];
        int slot = atomicAdd(&cur[r >> 7], 1);
        packed[slot] = make_int4(r, c, __float_as_int(a), 0);
    }
}

// ---------------- P4a: per-bucket counts + ea_sum (no global atomics) ----------------
__global__ __launch_bounds__(256) void k_p4a_deg(const int4* __restrict__ packed,
                                                 const int* __restrict__ bucket_base,
                                                 int* __restrict__ counts,
                                                 float* __restrict__ ea_sum) {
    __shared__ int   cnt[RPB];
    __shared__ float eas[RPB];
    int tid = threadIdx.x, b = blockIdx.x;
    if (tid < RPB) { cnt[tid] = 0; eas[tid] = 0.f; }
    __syncthreads();
    int s = bucket_base[b], e = bucket_base[b + 1];
    for (int i = s + tid; i < e; i += 256) {
        int4 p = packed[i];
        int lr = p.x & (RPB - 1);
        atomicAdd(&cnt[lr], 1);
        atomicAdd(&eas[lr], __int_as_float(p.z));
    }
    __syncthreads();
    int n = b * RPB + tid;
    if (tid < RPB && n < N_NODES) { counts[n] = cnt[tid]; ea_sum[n] = eas[tid]; }
}

// ---------------- single-block exclusive scan over counts[N] ----------------
__global__ __launch_bounds__(1024) void k_scan(const int* __restrict__ counts,
                                               int* __restrict__ offs) {
    const int T = 1024;
    const int CHUNK = (N_NODES + T - 1) / T; // 49
    __shared__ int sums[T];
    int t = threadIdx.x;
    int base = t * CHUNK;
    int s = 0;
    for (int i = 0; i < CHUNK; i++) {
        int idx = base + i;
        if (idx < N_NODES) s += counts[idx];
    }
    sums[t] = s;
    __syncthreads();
    for (int d = 1; d < T; d <<= 1) {
        int v = (t >= d) ? sums[t - d] : 0;
        __syncthreads();
        sums[t] += v;
        __syncthreads();
    }
    int excl = sums[t] - s;
    for (int i = 0; i < CHUNK; i++) {
        int idx = base + i;
        if (idx < N_NODES) { offs[idx] = excl; excl += counts[idx]; }
    }
    if (t == T - 1) offs[N_NODES] = excl; // == E
}

// ---------------- P4b: per-bucket scatter of col into csr (LDS cursors) ----------------
__global__ __launch_bounds__(256) void k_p4b_csr(const int4* __restrict__ packed,
                                                 const int* __restrict__ bucket_base,
                                                 const int* __restrict__ offs,
                                                 int* __restrict__ csr) {
    __shared__ int cur[RPB];
    int tid = threadIdx.x, b = blockIdx.x;
    int nbase = b * RPB;
    if (tid < RPB) cur[tid] = (nbase + tid < N_NODES) ? offs[nbase + tid] : 0;
    __syncthreads();
    int s = bucket_base[b], e = bucket_base[b + 1];
    for (int i = s + tid; i < e; i += 256) {
        int4 p = packed[i];
        int slot = atomicAdd(&cur[p.x & (RPB - 1)], 1);
        csr[slot] = p.y;
    }
}

// ------- precompute: transpose W2 (3 layers) + W7; v3[l] = W3[l] @ relu(W4[l]) -------
__global__ __launch_bounds__(256) void k_prep(const float* __restrict__ W2,
                                              const float* __restrict__ W7,
                                              const float* __restrict__ W3,
                                              const float* __restrict__ W4,
                                              float* __restrict__ w2t,
                                              float* __restrict__ w7t,
                                              float* __restrict__ v3) {
    int idx = blockIdx.x * 256 + threadIdx.x;
    if (idx < 4 * HID * HID) {
        int m = idx / (HID * HID), r = idx % (HID * HID);
        int hp = r / HID, h = r % HID; // source [hp][h]
        const float* src = (m < 3) ? (W2 + m * HID * HID) : W7;
        float*       dst = (m < 3) ? (w2t + m * HID * HID) : w7t;
        dst[h * HID + hp] = src[hp * HID + h];
    }
    if (idx < 3 * HID) {
        int l = idx / HID, hp = idx % HID;
        float acc = 0.f;
        for (int h = 0; h < HID; h++)
            acc += W3[l * HID * HID + hp * HID + h] * fmaxf(W4[l * HID + h], 0.f);
        v3[idx] = acc;
    }
}

// ---------------- hop 0: emb = relu(x*w1 + ea_sum*v3) ----------------
__global__ __launch_bounds__(256) void k_hop0(const float* __restrict__ x,
                                              const float* __restrict__ ea_sum,
                                              const float* __restrict__ w1,
                                              const float* __restrict__ v3,
                                              float* __restrict__ emb) {
    int idx = blockIdx.x * 256 + threadIdx.x;
    if (idx < N_NODES * HID) {
        int n = idx >> 7, h = idx & 127;
        emb[idx] = fmaxf(x[n] * w1[h] + ea_sum[n] * v3[h], 0.f);
    }
}

// ---------------- gather: agg[n] = sum over neighbors col of emb[col] ----------------
// one wave per node; lane holds an h-pair (float2); 4-wide unroll
__global__ __launch_bounds__(256) void k_gather(const float* __restrict__ emb,
                                                const int* __restrict__ offs,
                                                const int* __restrict__ csr,
                                                float* __restrict__ agg) {
    int wave = (blockIdx.x * 256 + threadIdx.x) >> 6;
    int lane = threadIdx.x & 63;
    if (wave >= N_NODES) return;
    int s = offs[wave], e = offs[wave + 1];
    const float2* eb = (const float2*)emb;
    float2 a0 = {0.f, 0.f}, a1 = {0.f, 0.f}, a2 = {0.f, 0.f}, a3 = {0.f, 0.f};
    int j = s;
    for (; j + 4 <= e; j += 4) {
        int c0 = csr[j], c1 = csr[j + 1], c2 = csr[j + 2], c3 = csr[j + 3];
        float2 v0 = eb[(size_t)c0 * 64 + lane];
        float2 v1 = eb[(size_t)c1 * 64 + lane];
        float2 v2 = eb[(size_t)c2 * 64 + lane];
        float2 v3 = eb[(size_t)c3 * 64 + lane];
        a0.x += v0.x; a0.y += v0.y;
        a1.x += v1.x; a1.y += v1.y;
        a2.x += v2.x; a2.y += v2.y;
        a3.x += v3.x; a3.y += v3.y;
    }
    for (; j < e; j++) {
        int c = csr[j];
        float2 v = eb[(size_t)c * 64 + lane];
        a0.x += v.x; a0.y += v.y;
    }
    float2 r; r.x = (a0.x + a1.x) + (a2.x + a3.x); r.y = (a0.y + a1.y) + (a2.y + a3.y);
    ((float2*)agg)[(size_t)wave * 64 + lane] = r;
}

// --------- in-place GEMM + fuse: buf[n] = relu(buf[n]@W2T + x[n]*w1 + ea_sum[n]*v3) ---------
__global__ __launch_bounds__(256) void k_gemm_relu(float* __restrict__ buf,
                                                   const float* __restrict__ w2tl,
                                                   const float* __restrict__ w1l,
                                                   const float* __restrict__ v3l,
                                                   const float* __restrict__ x,
                                                   const float* __restrict__ ea_sum) {
    __shared__ float tile[64 * HID]; // 32 KB
    int tid = threadIdx.x;
    int tbase = blockIdx.x * 64;
    const float4* src = (const float4*)(buf + (size_t)tbase * HID);
    float4* dst4 = (float4*)tile;
    int vn = N_NODES - tbase; if (vn > 64) vn = 64;
    int lim = vn * (HID / 4);
    for (int i = tid; i < 64 * HID / 4; i += 256) {
        float4 v = (i < lim) ? src[i] : float4{0.f, 0.f, 0.f, 0.f};
        dst4[i] = v;
    }
    __syncthreads();
    int w = tid >> 6, lane = tid & 63;
    float2 acc[16];
#pragma unroll
    for (int m = 0; m < 16; m++) acc[m] = {0.f, 0.f};
    const float2* w2 = (const float2*)w2tl;
#pragma unroll 2
    for (int h = 0; h < HID; h += 2) {
        float2 w0 = w2[h * 64 + lane];
        float2 w1 = w2[(h + 1) * 64 + lane];
        const float* trow = tile + (w * 16) * HID + h;
#pragma unroll
        for (int m = 0; m < 16; m++) {
            float2 a = *(const float2*)(trow + m * HID); // LDS broadcast
            acc[m].x += a.x * w0.x + a.y * w1.x;
            acc[m].y += a.x * w0.y + a.y * w1.y;
        }
    }
    float2 w1p = ((const float2*)w1l)[lane];
    float2 v3p = ((const float2*)v3l)[lane];
#pragma unroll
    for (int m = 0; m < 16; m++) {
        int n = tbase + w * 16 + m;
        if (n < N_NODES) {
            float xs = x[n], es = ea_sum[n];
            float2 r;
            r.x = fmaxf(acc[m].x + xs * w1p.x + es * v3p.x, 0.f);
            r.y = fmaxf(acc[m].y + xs * w1p.y + es * v3p.y, 0.f);
            ((float2*)buf)[(size_t)n * 64 + lane] = r;
        }
    }
}

// ---------------- graph pooling (batch sorted; per-block run-length accumulate) ----------------
__global__ __launch_bounds__(128) void k_pool(const float* __restrict__ emb,
                                              const int* __restrict__ batch,
                                              float* __restrict__ pooled) {
    const int CH = 256;
    int t = threadIdx.x;
    int start = blockIdx.x * CH;
    int end = start + CH; if (end > N_NODES) end = N_NODES;
    if (start >= N_NODES) return;
    float acc = 0.f;
    int cur = batch[start];
    for (int n = start; n < end; n++) {
        int g = batch[n];
        if (g != cur) { atomicAdd(&pooled[cur * HID + t], acc); acc = 0.f; cur = g; }
        acc += emb[(size_t)n * HID + t];
    }
    atomicAdd(&pooled[cur * HID + t], acc);
}

// ---------------- per-graph scalar: s_g = relu(pooled@W6T) . W5[:128] ----------------
__global__ __launch_bounds__(128) void k_graph(const float* __restrict__ pooled,
                                               const float* __restrict__ W6,
                                               const float* __restrict__ W5,
                                               float* __restrict__ s_g) {
    int g = blockIdx.x, hp = threadIdx.x;
    float acc = 0.f;
    for (int h = 0; h < HID; h++) acc += pooled[g * HID + h] * W6[hp * HID + h];
    float v = fmaxf(acc, 0.f) * W5[hp];
    __shared__ float red[HID];
    red[hp] = v;
    __syncthreads();
    for (int d = 64; d > 0; d >>= 1) {
        if (hp < d) red[hp] += red[hp + d];
        __syncthreads();
    }
    if (hp == 0) s_g[g] = red[0];
}

// ---------------- final: out[n] = s_{batch[n]} + relu(emb@W7T) . W5[128:] + b5 ----------------
__global__ __launch_bounds__(256) void k_final(const float* __restrict__ emb,
                                               const float* __restrict__ w7t,
                                               const float* __restrict__ W5,
                                               const float* __restrict__ b5,
                                               const int* __restrict__ batch,
                                               const float* __restrict__ s_g,
                                               float* __restrict__ out) {
    __shared__ float tile[64 * HID];
    int tid = threadIdx.x;
    int tbase = blockIdx.x * 64;
    const float4* src = (const float4*)(emb + (size_t)tbase * HID);
    float4* dst4 = (float4*)tile;
    int vn = N_NODES - tbase; if (vn > 64) vn = 64;
    int lim = vn * (HID / 4);
    for (int i = tid; i < 64 * HID / 4; i += 256) {
        float4 v = (i < lim) ? src[i] : float4{0.f, 0.f, 0.f, 0.f};
        dst4[i] = v;
    }
    __syncthreads();
    int w = tid >> 6, lane = tid & 63;
    float2 acc[16];
#pragma unroll
    for (int m = 0; m < 16; m++) acc[m] = {0.f, 0.f};
    const float2* w7 = (const float2*)w7t;
#pragma unroll 2
    for (int h = 0; h < HID; h += 2) {
        float2 w0 = w7[h * 64 + lane];
        float2 w1 = w7[(h + 1) * 64 + lane];
        const float* trow = tile + (w * 16) * HID + h;
#pragma unroll
        for (int m = 0; m < 16; m++) {
            float2 a = *(const float2*)(trow + m * HID);
            acc[m].x += a.x * w0.x + a.y * w1.x;
            acc[m].y += a.x * w0.y + a.y * w1.y;
        }
    }
    float2 w5p = ((const float2*)W5)[64 + lane];
    float bias = b5[0];
#pragma unroll
    for (int m = 0; m < 16; m++) {
        float p = fmaxf(acc[m].x, 0.f) * w5p.x + fmaxf(acc[m].y, 0.f) * w5p.y;
        for (int off = 32; off > 0; off >>= 1) p += __shfl_down(p, off);
        int n = tbase + w * 16 + m;
        if (lane == 0 && n < N_NODES) out[n] = p + s_g[batch[n]] + bias;
    }
}

extern "C" void kernel_launch(void* const* d_in, const int* in_sizes, int n_in,
                              void* d_out, int out_size, void* d_ws, size_t ws_size,
                              hipStream_t stream) {
    (void)in_sizes; (void)n_in; (void)out_size; (void)ws_size;
    const float* x    = (const float*)d_in[0];
    const int*   ei   = (const int*)d_in[1];   // [2,E] flat: row then col
    const float* ea   = (const float*)d_in[2];
    const int*   bat  = (const int*)d_in[3];
    const float* W1   = (const float*)d_in[4]; // [3,128,1]
    const float* W2   = (const float*)d_in[5]; // [3,128,128]
    const float* W3   = (const float*)d_in[6];
    const float* W4   = (const float*)d_in[7]; // [3,128,1]
    const float* W5   = (const float*)d_in[8]; // [1,256]
    const float* b5   = (const float*)d_in[9];
    const float* W6   = (const float*)d_in[10];
    const float* W7   = (const float*)d_in[11];
    float* out = (float*)d_out;

    const int* row = ei;
    const int* col = ei + N_EDGES;

    // workspace layout (4B elems; embA/embB 16B-aligned)
    float* wsf = (float*)d_ws;
    int*   wsi = (int*)d_ws;
    size_t o = 0;
    float* pooled = wsf + o; o += NGRAPH * HID;     // zeroed (atomic targets)
    float* s_g    = wsf + o; o += NGRAPH;           // zeroed
    size_t ztot = o;                                // 2064
    int*   offs   = wsi + o; o += N_NODES + 1;
    int*   counts = wsi + o; o += N_NODES;
    float* ea_sum = wsf + o; o += N_NODES;
    int*   bbase  = wsi + o; o += NB + 1;
    int*   blkh   = wsi + o; o += NB * NBLK;
    float* v3     = wsf + o; o += 3 * HID;
    float* w2t    = wsf + o; o += 3 * HID * HID;
    float* w7t    = wsf + o; o += HID * HID;
    int*   csr    = wsi + o; o += N_EDGES; o = (o + 3) & ~(size_t)3;
    float* embA   = wsf + o; o += (size_t)N_NODES * HID;
    float* embB   = wsf + o; o += (size_t)N_NODES * HID;
    int4*  packed = (int4*)embB;  // aliased: fully consumed before first gather writes embB

    // 0) zero atomic accumulators (pooled, s_g)
    k_zero<<<(int)((ztot + 255) / 256), 256, 0, stream>>>((float*)d_ws, (int)ztot);
    // 1) atomic-free CSR build
    k_p1_hist<<<NBLK, 256, 0, stream>>>(row, blkh);
    k_p2_scan<<<1, 512, 0, stream>>>(blkh, bbase);
    k_p3_part<<<NBLK, 256, 0, stream>>>(row, col, ea, blkh, packed);
    k_p4a_deg<<<NB, 256, 0, stream>>>(packed, bbase, counts, ea_sum);
    k_scan<<<1, 1024, 0, stream>>>(counts, offs);
    k_p4b_csr<<<NB, 256, 0, stream>>>(packed, bbase, offs, csr);
    // 2) weight precompute: W2T (x3), W7T, v3
    k_prep<<<(4 * HID * HID + 255) / 256, 256, 0, stream>>>(W2, W7, W3, W4, w2t, w7t, v3);
    // 3) hop 0 (elementwise) -> embA
    k_hop0<<<(N_NODES * HID + 255) / 256, 256, 0, stream>>>(x, ea_sum, W1, v3, embA);
    // 4) hop 1: gather embA->embB, GEMM in-place on embB
    k_gather<<<(N_NODES * 64) / 256, 256, 0, stream>>>(embA, offs, csr, embB);
    k_gemm_relu<<<(N_NODES + 63) / 64, 256, 0, stream>>>(embB, w2t + 1 * HID * HID,
                                                         W1 + 1 * HID, v3 + 1 * HID, x, ea_sum);
    // 5) hop 2: gather embB->embA, GEMM in-place on embA
    k_gather<<<(N_NODES * 64) / 256, 256, 0, stream>>>(embB, offs, csr, embA);
    k_gemm_relu<<<(N_NODES + 63) / 64, 256, 0, stream>>>(embA, w2t + 2 * HID * HID,
                                                         W1 + 2 * HID, v3 + 2 * HID, x, ea_sum);
    // 6) graph pooling
    k_pool<<<(N_NODES + 255) / 256, 128, 0, stream>>>(embA, bat, pooled);
    // 7) per-graph scalars
    k_graph<<<NGRAPH, 128, 0, stream>>>(pooled, W6, W5, s_g);
    // 8) final head
    k_final<<<(N_NODES + 63) / 64, 256, 0, stream>>>(embA, w7t, W5, b5, bat, s_g, out);
}

// Round 3
// 690.102 us; speedup vs baseline: 1.3878x; 1.0690x over previous
//
#include <hip/hip_runtime.h>
#include <hip/hip_bf16.h>

#define N_NODES 50000
#define N_EDGES 1600000
#define NGRAPH  16
#define HID     128

#define RPB   128                           // rows per bucket
#define NB    ((N_NODES + RPB - 1) / RPB)   // 391 buckets
#define NBLK  64                            // partition blocks
#define EPB   ((N_EDGES + NBLK - 1) / NBLK) // 25000 edges per partition block

typedef unsigned int uint32;

// bf16 round-to-nearest-even pack helpers (values are post-relu, no NaN)
__device__ __forceinline__ uint32 bf16r(float f) {
    uint32 b = __float_as_uint(f);
    return (b + 0x7fffu + ((b >> 16) & 1u)) >> 16;
}
__device__ __forceinline__ uint32 pack_bf16(float lo, float hi) {
    return bf16r(lo) | (bf16r(hi) << 16);
}

// ---------------- zero init (ws poisoned 0xAA every call) ----------------
__global__ __launch_bounds__(256) void k_zero(float* p, int n) {
    int i = blockIdx.x * 256 + threadIdx.x;
    if (i < n) p[i] = 0.f;
}

// ---------------- P1: per-(bucket,block) histogram (LDS atomics only) ----------------
__global__ __launch_bounds__(256) void k_p1_hist(const int* __restrict__ row,
                                                 int* __restrict__ blkhist) {
    __shared__ int hist[NB];
    int tid = threadIdx.x, blk = blockIdx.x;
    for (int i = tid; i < NB; i += 256) hist[i] = 0;
    __syncthreads();
    int s = blk * EPB, e = s + EPB; if (e > N_EDGES) e = N_EDGES;
    for (int i = s + tid; i < e; i += 256)
        atomicAdd(&hist[row[i] >> 7], 1);
    __syncthreads();
    for (int i = tid; i < NB; i += 256)
        blkhist[i * NBLK + blk] = hist[i];
}

// ---------------- P2: bucket bases + per-(bucket,block) cursors (one block) ----------------
__global__ __launch_bounds__(512) void k_p2_scan(int* __restrict__ blkhist,
                                                 int* __restrict__ bucket_base) {
    __shared__ int sums[512];
    int t = threadIdx.x;
    int s = 0;
    if (t < NB)
        for (int k = 0; k < NBLK; k++) s += blkhist[t * NBLK + k];
    sums[t] = s;
    __syncthreads();
    for (int d = 1; d < 512; d <<= 1) {
        int v = (t >= d) ? sums[t - d] : 0;
        __syncthreads();
        sums[t] += v;
        __syncthreads();
    }
    if (t < NB) {
        int excl = sums[t] - s;
        bucket_base[t] = excl;
        int run = excl;
        for (int k = 0; k < NBLK; k++) {
            int tmp = blkhist[t * NBLK + k];
            blkhist[t * NBLK + k] = run;   // becomes per-(bucket,block) base
            run += tmp;
        }
        if (t == NB - 1) bucket_base[NB] = run; // == E
    }
}

// ------- P3: scatter {rowlocal:8|col:16} + ea into bucket runs (LDS cursors) -------
__global__ __launch_bounds__(256) void k_p3_part(const int* __restrict__ row,
                                                 const int* __restrict__ col,
                                                 const float* __restrict__ ea,
                                                 const int* __restrict__ blkbase,
                                                 uint32* __restrict__ packed,
                                                 float* __restrict__ eaq) {
    __shared__ int cur[NB];
    int tid = threadIdx.x, blk = blockIdx.x;
    for (int i = tid; i < NB; i += 256) cur[i] = blkbase[i * NBLK + blk];
    __syncthreads();
    int s = blk * EPB, e = s + EPB; if (e > N_EDGES) e = N_EDGES;
    for (int i = s + tid; i < e; i += 256) {
        int r = row[i], c = col[i];
        float a = ea[i];
        int slot = atomicAdd(&cur[r >> 7], 1);
        packed[slot] = ((uint32)(r & (RPB - 1)) << 16) | (uint32)c;  // col < 65536
        eaq[slot] = a;
    }
}

// ------- P4: per-bucket counts + ea_sum + local scan -> offs; then scatter csr -------
__global__ __launch_bounds__(256) void k_p4(const uint32* __restrict__ packed,
                                            const float* __restrict__ eaq,
                                            const int* __restrict__ bbase,
                                            int* __restrict__ offs,
                                            float* __restrict__ ea_sum,
                                            int* __restrict__ csr) {
    __shared__ int   cnt[RPB];
    __shared__ float eas[RPB];
    __shared__ int   scan_s[RPB];
    __shared__ int   cur[RPB];
    int tid = threadIdx.x, b = blockIdx.x;
    if (tid < RPB) { cnt[tid] = 0; eas[tid] = 0.f; }
    __syncthreads();
    int s = bbase[b], e = bbase[b + 1];
    for (int i = s + tid; i < e; i += 256) {
        uint32 p = packed[i];
        int lr = p >> 16;
        atomicAdd(&cnt[lr], 1);
        atomicAdd(&eas[lr], eaq[i]);
    }
    __syncthreads();
    if (tid < RPB) scan_s[tid] = cnt[tid];
    __syncthreads();
    for (int d = 1; d < RPB; d <<= 1) {
        int v = 0;
        if (tid < RPB && tid >= d) v = scan_s[tid - d];
        __syncthreads();
        if (tid < RPB) scan_s[tid] += v;
        __syncthreads();
    }
    int nbase = b * RPB;
    if (tid < RPB) {
        int excl = scan_s[tid] - cnt[tid];
        int n = nbase + tid;
        if (n < N_NODES) { offs[n] = s + excl; ea_sum[n] = eas[tid]; }
        cur[tid] = s + excl;
    }
    if (b == NB - 1 && tid == 0) offs[N_NODES] = e; // == E
    __syncthreads();
    for (int i = s + tid; i < e; i += 256) {
        uint32 p = packed[i];
        int slot = atomicAdd(&cur[p >> 16], 1);
        csr[slot] = (int)(p & 0xFFFFu);
    }
}

// ------- precompute: transpose W2 (3 layers) + W7; v3[l] = W3[l] @ relu(W4[l]) -------
__global__ __launch_bounds__(256) void k_prep(const float* __restrict__ W2,
                                              const float* __restrict__ W7,
                                              const float* __restrict__ W3,
                                              const float* __restrict__ W4,
                                              float* __restrict__ w2t,
                                              float* __restrict__ w7t,
                                              float* __restrict__ v3) {
    int idx = blockIdx.x * 256 + threadIdx.x;
    if (idx < 4 * HID * HID) {
        int m = idx / (HID * HID), r = idx % (HID * HID);
        int hp = r / HID, h = r % HID; // source [hp][h]
        const float* src = (m < 3) ? (W2 + m * HID * HID) : W7;
        float*       dst = (m < 3) ? (w2t + m * HID * HID) : w7t;
        dst[h * HID + hp] = src[hp * HID + h];
    }
    if (idx < 3 * HID) {
        int l = idx / HID, hp = idx % HID;
        float acc = 0.f;
        for (int h = 0; h < HID; h++)
            acc += W3[l * HID * HID + hp * HID + h] * fmaxf(W4[l * HID + h], 0.f);
        v3[idx] = acc;
    }
}

// ---------------- hop 0: emb(bf16) = relu(x*w1 + ea_sum*v3) ----------------
__global__ __launch_bounds__(256) void k_hop0(const float* __restrict__ x,
                                              const float* __restrict__ ea_sum,
                                              const float* __restrict__ w1,
                                              const float* __restrict__ v3,
                                              uint32* __restrict__ emb) {
    int idx = blockIdx.x * 256 + threadIdx.x; // over N*64
    if (idx < N_NODES * 64) {
        int n = idx >> 6, l = idx & 63;
        float xs = x[n], es = ea_sum[n];
        float r0 = fmaxf(xs * w1[2 * l]     + es * v3[2 * l],     0.f);
        float r1 = fmaxf(xs * w1[2 * l + 1] + es * v3[2 * l + 1], 0.f);
        emb[idx] = pack_bf16(r0, r1);
    }
}

// ------- fused hop: gather(bf16 emb) -> LDS tile -> GEMM W2 + relu -> bf16 embOut -------
// LAST additionally: tile <- new emb; GEMM W7; out[n] = relu(.)·W5[128:] (partial, no s_g/bias)
template <bool LAST>
__global__ __launch_bounds__(256) void k_hop_t(const uint32* __restrict__ embIn,
                                               const int* __restrict__ offs,
                                               const int* __restrict__ csr,
                                               const float* __restrict__ x,
                                               const float* __restrict__ ea_sum,
                                               const float* __restrict__ w2tl,
                                               const float* __restrict__ w1l,
                                               const float* __restrict__ v3l,
                                               uint32* __restrict__ embOut,
                                               const float* __restrict__ w7t,
                                               const float* __restrict__ W5,
                                               float* __restrict__ outp) {
    __shared__ float tile[64 * HID]; // 32 KB
    int tid = threadIdx.x, w = tid >> 6, lane = tid & 63;
    int tbase = blockIdx.x * 64;
    int rowbase = w * 16;
    // gather phase: wave w fills its own 16 tile rows
    for (int m = 0; m < 16; m++) {
        int n = tbase + rowbase + m;
        float2 a0 = {0.f, 0.f}, a1 = {0.f, 0.f}, a2 = {0.f, 0.f}, a3 = {0.f, 0.f};
        if (n < N_NODES) {
            int s = offs[n], e = offs[n + 1];
            int j = s;
            for (; j + 4 <= e; j += 4) {
                int c0 = csr[j], c1 = csr[j + 1], c2 = csr[j + 2], c3 = csr[j + 3];
                uint32 u0 = embIn[(size_t)c0 * 64 + lane];
                uint32 u1 = embIn[(size_t)c1 * 64 + lane];
                uint32 u2 = embIn[(size_t)c2 * 64 + lane];
                uint32 u3 = embIn[(size_t)c3 * 64 + lane];
                a0.x += __uint_as_float(u0 << 16); a0.y += __uint_as_float(u0 & 0xffff0000u);
                a1.x += __uint_as_float(u1 << 16); a1.y += __uint_as_float(u1 & 0xffff0000u);
                a2.x += __uint_as_float(u2 << 16); a2.y += __uint_as_float(u2 & 0xffff0000u);
                a3.x += __uint_as_float(u3 << 16); a3.y += __uint_as_float(u3 & 0xffff0000u);
            }
            for (; j < e; j++) {
                uint32 u = embIn[(size_t)csr[j] * 64 + lane];
                a0.x += __uint_as_float(u << 16); a0.y += __uint_as_float(u & 0xffff0000u);
            }
        }
        float2 r;
        r.x = (a0.x + a1.x) + (a2.x + a3.x);
        r.y = (a0.y + a1.y) + (a2.y + a3.y);
        *(float2*)&tile[(rowbase + m) * HID + 2 * lane] = r;
    }
    __syncthreads();
    // GEMM-1: emb = relu(agg @ W2T + x*w1 + ea*v3)
    float2 acc[16];
#pragma unroll
    for (int m = 0; m < 16; m++) acc[m] = {0.f, 0.f};
    const float2* w2 = (const float2*)w2tl;
#pragma unroll 2
    for (int h = 0; h < HID; h += 2) {
        float2 w0 = w2[h * 64 + lane];
        float2 w1 = w2[(h + 1) * 64 + lane];
        const float* trow = tile + rowbase * HID + h;
#pragma unroll
        for (int m = 0; m < 16; m++) {
            float2 a = *(const float2*)(trow + m * HID); // LDS broadcast
            acc[m].x += a.x * w0.x + a.y * w1.x;
            acc[m].y += a.x * w0.y + a.y * w1.y;
        }
    }
    float2 w1p = ((const float2*)w1l)[lane];
    float2 v3p = ((const float2*)v3l)[lane];
#pragma unroll
    for (int m = 0; m < 16; m++) {
        int n = tbase + rowbase + m;
        float xs = 0.f, es = 0.f;
        if (n < N_NODES) { xs = x[n]; es = ea_sum[n]; }
        float2 r;
        r.x = fmaxf(acc[m].x + xs * w1p.x + es * v3p.x, 0.f);
        r.y = fmaxf(acc[m].y + xs * w1p.y + es * v3p.y, 0.f);
        if (n < N_NODES) embOut[(size_t)n * 64 + lane] = pack_bf16(r.x, r.y);
        if (LAST) {
            *(float2*)&tile[(rowbase + m) * HID + 2 * lane] = r; // wave-private rows
            acc[m] = {0.f, 0.f};
        }
    }
    if (LAST) {
        // GEMM-2: relu(emb @ W7T) . W5[128:] -> partial out
        const float2* w7 = (const float2*)w7t;
#pragma unroll 2
        for (int h = 0; h < HID; h += 2) {
            float2 w0 = w7[h * 64 + lane];
            float2 w1 = w7[(h + 1) * 64 + lane];
            const float* trow = tile + rowbase * HID + h;
#pragma unroll
            for (int m = 0; m < 16; m++) {
                float2 a = *(const float2*)(trow + m * HID);
                acc[m].x += a.x * w0.x + a.y * w1.x;
                acc[m].y += a.x * w0.y + a.y * w1.y;
            }
        }
        float2 w5p = ((const float2*)W5)[64 + lane];
#pragma unroll
        for (int m = 0; m < 16; m++) {
            float p = fmaxf(acc[m].x, 0.f) * w5p.x + fmaxf(acc[m].y, 0.f) * w5p.y;
            for (int off = 32; off > 0; off >>= 1) p += __shfl_down(p, off);
            int n = tbase + rowbase + m;
            if (lane == 0 && n < N_NODES) outp[n] = p;
        }
    }
}

// ---------------- graph pooling over bf16 emb (batch sorted) ----------------
__global__ __launch_bounds__(128) void k_pool(const unsigned short* __restrict__ emb16,
                                              const int* __restrict__ batch,
                                              float* __restrict__ pooled) {
    const int CH = 256;
    int t = threadIdx.x;
    int start = blockIdx.x * CH;
    int end = start + CH; if (end > N_NODES) end = N_NODES;
    if (start >= N_NODES) return;
    float acc = 0.f;
    int cur = batch[start];
    for (int n = start; n < end; n++) {
        int g = batch[n];
        if (g != cur) { atomicAdd(&pooled[cur * HID + t], acc); acc = 0.f; cur = g; }
        acc += __uint_as_float(((uint32)emb16[(size_t)n * HID + t]) << 16);
    }
    atomicAdd(&pooled[cur * HID + t], acc);
}

// ---------------- per-graph scalar: s_g = relu(pooled@W6T) . W5[:128] ----------------
__global__ __launch_bounds__(128) void k_graph(const float* __restrict__ pooled,
                                               const float* __restrict__ W6,
                                               const float* __restrict__ W5,
                                               float* __restrict__ s_g) {
    int g = blockIdx.x, hp = threadIdx.x;
    float acc = 0.f;
    for (int h = 0; h < HID; h++) acc += pooled[g * HID + h] * W6[hp * HID + h];
    float v = fmaxf(acc, 0.f) * W5[hp];
    __shared__ float red[HID];
    red[hp] = v;
    __syncthreads();
    for (int d = 64; d > 0; d >>= 1) {
        if (hp < d) red[hp] += red[hp + d];
        __syncthreads();
    }
    if (hp == 0) s_g[g] = red[0];
}

// ---------------- final add: out[n] += s_g[batch[n]] + b5 ----------------
__global__ __launch_bounds__(256) void k_addsg(float* __restrict__ out,
                                               const int* __restrict__ batch,
                                               const float* __restrict__ s_g,
                                               const float* __restrict__ b5) {
    int n = blockIdx.x * 256 + threadIdx.x;
    if (n < N_NODES) out[n] += s_g[batch[n]] + b5[0];
}

extern "C" void kernel_launch(void* const* d_in, const int* in_sizes, int n_in,
                              void* d_out, int out_size, void* d_ws, size_t ws_size,
                              hipStream_t stream) {
    (void)in_sizes; (void)n_in; (void)out_size; (void)ws_size;
    const float* x    = (const float*)d_in[0];
    const int*   ei   = (const int*)d_in[1];   // [2,E] flat: row then col
    const float* ea   = (const float*)d_in[2];
    const int*   bat  = (const int*)d_in[3];
    const float* W1   = (const float*)d_in[4]; // [3,128,1]
    const float* W2   = (const float*)d_in[5]; // [3,128,128]
    const float* W3   = (const float*)d_in[6];
    const float* W4   = (const float*)d_in[7]; // [3,128,1]
    const float* W5   = (const float*)d_in[8]; // [1,256]
    const float* b5   = (const float*)d_in[9];
    const float* W6   = (const float*)d_in[10];
    const float* W7   = (const float*)d_in[11];
    float* out = (float*)d_out;

    const int* row = ei;
    const int* col = ei + N_EDGES;

    // workspace layout (4B elems)
    float* wsf = (float*)d_ws;
    int*   wsi = (int*)d_ws;
    size_t o = 0;
    float* pooled = wsf + o; o += NGRAPH * HID;     // zeroed (atomic targets)
    float* s_g    = wsf + o; o += NGRAPH;           // zeroed
    size_t ztot = o;                                // 2064
    int*   offs   = wsi + o; o += N_NODES + 1;
    float* ea_sum = wsf + o; o += N_NODES;
    int*   bbase  = wsi + o; o += NB + 1;
    int*   blkh   = wsi + o; o += NB * NBLK;
    float* v3     = wsf + o; o += 3 * HID;
    float* w2t    = wsf + o; o += 3 * HID * HID;
    float* w7t    = wsf + o; o += HID * HID;
    int*    csr    = wsi + o;           o += N_EDGES;
    uint32* packed = (uint32*)(wsi + o); o += N_EDGES;
    float*  eaq    = wsf + o;           o += N_EDGES;
    o = (o + 3) & ~(size_t)3;
    uint32* embA   = (uint32*)(wsi + o); o += (size_t)N_NODES * 64; // bf16 [N][128]
    uint32* embB   = (uint32*)(wsi + o); o += (size_t)N_NODES * 64;

    // 0) zero atomic accumulators (pooled, s_g)
    k_zero<<<(int)((ztot + 255) / 256), 256, 0, stream>>>((float*)d_ws, (int)ztot);
    // 1) atomic-free CSR build
    k_p1_hist<<<NBLK, 256, 0, stream>>>(row, blkh);
    k_p2_scan<<<1, 512, 0, stream>>>(blkh, bbase);
    k_p3_part<<<NBLK, 256, 0, stream>>>(row, col, ea, blkh, packed, eaq);
    k_p4<<<NB, 256, 0, stream>>>(packed, eaq, bbase, offs, ea_sum, csr);
    // 2) weight precompute: W2T (x3), W7T, v3
    k_prep<<<(4 * HID * HID + 255) / 256, 256, 0, stream>>>(W2, W7, W3, W4, w2t, w7t, v3);
    // 3) hop 0 (elementwise) -> embA (bf16)
    k_hop0<<<(N_NODES * 64 + 255) / 256, 256, 0, stream>>>(x, ea_sum, W1, v3, embA);
    // 4) hop 1: fused gather+GEMM, embA -> embB
    k_hop_t<false><<<(N_NODES + 63) / 64, 256, 0, stream>>>(
        embA, offs, csr, x, ea_sum, w2t + 1 * HID * HID, W1 + 1 * HID, v3 + 1 * HID,
        embB, nullptr, nullptr, nullptr);
    // 5) hop 2: fused gather+GEMM + W7 head partial, embB -> embA, out partial
    k_hop_t<true><<<(N_NODES + 63) / 64, 256, 0, stream>>>(
        embB, offs, csr, x, ea_sum, w2t + 2 * HID * HID, W1 + 2 * HID, v3 + 2 * HID,
        embA, w7t, W5, out);
    // 6) graph pooling (bf16 emb)
    k_pool<<<(N_NODES + 255) / 256, 128, 0, stream>>>((const unsigned short*)embA, bat, pooled);
    // 7) per-graph scalars
    k_graph<<<NGRAPH, 128, 0, stream>>>(pooled, W6, W5, s_g);
    // 8) add graph term + bias
    k_addsg<<<(N_NODES + 255) / 256, 256, 0, stream>>>(out, bat, s_g, b5);
}

// Round 4
// 541.653 us; speedup vs baseline: 1.7682x; 1.2741x over previous
//
#include <hip/hip_runtime.h>
#include <hip/hip_bf16.h>

#define N_NODES 50000
#define N_EDGES 1600000
#define NGRAPH  16
#define HID     128

#define RPB   128                           // rows per bucket
#define NB    ((N_NODES + RPB - 1) / RPB)   // 391 buckets
#define NBLK  64                            // partition blocks
#define EPB   ((N_EDGES + NBLK - 1) / NBLK) // 25000 edges per partition block

typedef unsigned int uint32;

// bf16 round-to-nearest-even pack helpers
__device__ __forceinline__ uint32 bf16r(float f) {
    uint32 b = __float_as_uint(f);
    return (b + 0x7fffu + ((b >> 16) & 1u)) >> 16;
}
__device__ __forceinline__ uint32 pack_bf16(float lo, float hi) {
    return bf16r(lo) | (bf16r(hi) << 16);
}
__device__ __forceinline__ float bf_lo(uint32 u) { return __uint_as_float(u << 16); }
__device__ __forceinline__ float bf_hi(uint32 u) { return __uint_as_float(u & 0xffff0000u); }

// ---------------- zero init ----------------
__global__ __launch_bounds__(256) void k_zero(float* p, int n) {
    int i = blockIdx.x * 256 + threadIdx.x;
    if (i < n) p[i] = 0.f;
}

// ---------------- P1: per-(bucket,block) histogram (LDS atomics only) ----------------
__global__ __launch_bounds__(256) void k_p1_hist(const int* __restrict__ row,
                                                 int* __restrict__ blkhist) {
    __shared__ int hist[NB];
    int tid = threadIdx.x, blk = blockIdx.x;
    for (int i = tid; i < NB; i += 256) hist[i] = 0;
    __syncthreads();
    int s = blk * EPB, e = s + EPB; if (e > N_EDGES) e = N_EDGES;
    for (int i = s + tid; i < e; i += 256)
        atomicAdd(&hist[row[i] >> 7], 1);
    __syncthreads();
    for (int i = tid; i < NB; i += 256)
        blkhist[i * NBLK + blk] = hist[i];
}

// ---------------- P2: bucket bases + per-(bucket,block) cursors (one block) ----------------
__global__ __launch_bounds__(512) void k_p2_scan(int* __restrict__ blkhist,
                                                 int* __restrict__ bucket_base) {
    __shared__ int sums[512];
    int t = threadIdx.x;
    int s = 0;
    if (t < NB)
        for (int k = 0; k < NBLK; k++) s += blkhist[t * NBLK + k];
    sums[t] = s;
    __syncthreads();
    for (int d = 1; d < 512; d <<= 1) {
        int v = (t >= d) ? sums[t - d] : 0;
        __syncthreads();
        sums[t] += v;
        __syncthreads();
    }
    if (t < NB) {
        int excl = sums[t] - s;
        bucket_base[t] = excl;
        int run = excl;
        for (int k = 0; k < NBLK; k++) {
            int tmp = blkhist[t * NBLK + k];
            blkhist[t * NBLK + k] = run;
            run += tmp;
        }
        if (t == NB - 1) bucket_base[NB] = run; // == E
    }
}

// ------- P3: scatter {rowlocal:8|col:16} + ea into bucket runs (LDS cursors) -------
__global__ __launch_bounds__(256) void k_p3_part(const int* __restrict__ row,
                                                 const int* __restrict__ col,
                                                 const float* __restrict__ ea,
                                                 const int* __restrict__ blkbase,
                                                 uint32* __restrict__ packed,
                                                 float* __restrict__ eaq) {
    __shared__ int cur[NB];
    int tid = threadIdx.x, blk = blockIdx.x;
    for (int i = tid; i < NB; i += 256) cur[i] = blkbase[i * NBLK + blk];
    __syncthreads();
    int s = blk * EPB, e = s + EPB; if (e > N_EDGES) e = N_EDGES;
    for (int i = s + tid; i < e; i += 256) {
        int r = row[i], c = col[i];
        float a = ea[i];
        int slot = atomicAdd(&cur[r >> 7], 1);
        packed[slot] = ((uint32)(r & (RPB - 1)) << 16) | (uint32)c;  // col < 65536
        eaq[slot] = a;
    }
}

// ------- P4: per-bucket counts + ea_sum + local scan -> offs; then scatter csr -------
__global__ __launch_bounds__(256) void k_p4(const uint32* __restrict__ packed,
                                            const float* __restrict__ eaq,
                                            const int* __restrict__ bbase,
                                            int* __restrict__ offs,
                                            float* __restrict__ ea_sum,
                                            int* __restrict__ csr) {
    __shared__ int   cnt[RPB];
    __shared__ float eas[RPB];
    __shared__ int   scan_s[RPB];
    __shared__ int   cur[RPB];
    int tid = threadIdx.x, b = blockIdx.x;
    if (tid < RPB) { cnt[tid] = 0; eas[tid] = 0.f; }
    __syncthreads();
    int s = bbase[b], e = bbase[b + 1];
    for (int i = s + tid; i < e; i += 256) {
        uint32 p = packed[i];
        int lr = p >> 16;
        atomicAdd(&cnt[lr], 1);
        atomicAdd(&eas[lr], eaq[i]);
    }
    __syncthreads();
    if (tid < RPB) scan_s[tid] = cnt[tid];
    __syncthreads();
    for (int d = 1; d < RPB; d <<= 1) {
        int v = 0;
        if (tid < RPB && tid >= d) v = scan_s[tid - d];
        __syncthreads();
        if (tid < RPB) scan_s[tid] += v;
        __syncthreads();
    }
    int nbase = b * RPB;
    if (tid < RPB) {
        int excl = scan_s[tid] - cnt[tid];
        int n = nbase + tid;
        if (n < N_NODES) { offs[n] = s + excl; ea_sum[n] = eas[tid]; }
        cur[tid] = s + excl;
    }
    if (b == NB - 1 && tid == 0) offs[N_NODES] = e;
    __syncthreads();
    for (int i = s + tid; i < e; i += 256) {
        uint32 p = packed[i];
        int slot = atomicAdd(&cur[p >> 16], 1);
        csr[slot] = (int)(p & 0xFFFFu);
    }
}

// ------- precompute: transpose W2 (3 layers) + W7; v3[l] = W3[l] @ relu(W4[l]) -------
__global__ __launch_bounds__(256) void k_prep(const float* __restrict__ W2,
                                              const float* __restrict__ W7,
                                              const float* __restrict__ W3,
                                              const float* __restrict__ W4,
                                              float* __restrict__ w2t,
                                              float* __restrict__ w7t,
                                              float* __restrict__ v3) {
    int idx = blockIdx.x * 256 + threadIdx.x;
    if (idx < 4 * HID * HID) {
        int m = idx / (HID * HID), r = idx % (HID * HID);
        int hp = r / HID, h = r % HID;
        const float* src = (m < 3) ? (W2 + m * HID * HID) : W7;
        float*       dst = (m < 3) ? (w2t + m * HID * HID) : w7t;
        dst[h * HID + hp] = src[hp * HID + h];
    }
    if (idx < 3 * HID) {
        int l = idx / HID, hp = idx % HID;
        float acc = 0.f;
        for (int h = 0; h < HID; h++)
            acc += W3[l * HID * HID + hp * HID + h] * fmaxf(W4[l * HID + h], 0.f);
        v3[idx] = acc;
    }
}

// ---------------- hop 0: emb(bf16) = relu(x*w1 + ea_sum*v3) ----------------
__global__ __launch_bounds__(256) void k_hop0(const float* __restrict__ x,
                                              const float* __restrict__ ea_sum,
                                              const float* __restrict__ w1,
                                              const float* __restrict__ v3,
                                              uint32* __restrict__ emb) {
    int idx = blockIdx.x * 256 + threadIdx.x; // over N*64
    if (idx < N_NODES * 64) {
        int n = idx >> 6, l = idx & 63;
        float xs = x[n], es = ea_sum[n];
        float r0 = fmaxf(xs * w1[2 * l]     + es * v3[2 * l],     0.f);
        float r1 = fmaxf(xs * w1[2 * l + 1] + es * v3[2 * l + 1], 0.f);
        emb[idx] = pack_bf16(r0, r1);
    }
}

// ------- gather: agg(bf16)[n] = sum over neighbors of emb(bf16)[col] -------
// one wave per node; lane holds an h-pair packed in uint32; 4-wide unroll
__global__ __launch_bounds__(256) void k_gather(const uint32* __restrict__ emb,
                                                const int* __restrict__ offs,
                                                const int* __restrict__ csr,
                                                uint32* __restrict__ agg) {
    int node = (blockIdx.x * 256 + threadIdx.x) >> 6;
    int lane = threadIdx.x & 63;
    if (node >= N_NODES) return;
    int s = offs[node], e = offs[node + 1];
    float2 a0 = {0.f, 0.f}, a1 = {0.f, 0.f}, a2 = {0.f, 0.f}, a3 = {0.f, 0.f};
    int j = s;
    for (; j + 4 <= e; j += 4) {
        int c0 = csr[j], c1 = csr[j + 1], c2 = csr[j + 2], c3 = csr[j + 3];
        uint32 u0 = emb[(size_t)c0 * 64 + lane];
        uint32 u1 = emb[(size_t)c1 * 64 + lane];
        uint32 u2 = emb[(size_t)c2 * 64 + lane];
        uint32 u3 = emb[(size_t)c3 * 64 + lane];
        a0.x += bf_lo(u0); a0.y += bf_hi(u0);
        a1.x += bf_lo(u1); a1.y += bf_hi(u1);
        a2.x += bf_lo(u2); a2.y += bf_hi(u2);
        a3.x += bf_lo(u3); a3.y += bf_hi(u3);
    }
    for (; j < e; j++) {
        uint32 u = emb[(size_t)csr[j] * 64 + lane];
        a0.x += bf_lo(u); a0.y += bf_hi(u);
    }
    float rx = (a0.x + a1.x) + (a2.x + a3.x);
    float ry = (a0.y + a1.y) + (a2.y + a3.y);
    agg[(size_t)node * 64 + lane] = pack_bf16(rx, ry);
}

// ------- 16-node x 128x128 GEMM inner: acc += tile_rows @ W^T (pipelined weights) -------
__device__ __forceinline__ void gemm16(const float* trowbase, const float2* wmat,
                                       int lane, float2 acc[16]) {
    float2 wreg[4];
#pragma unroll
    for (int i = 0; i < 4; i++) wreg[i] = wmat[i * 64 + lane];
    for (int hb = 0; hb < HID; hb += 4) {
        float2 wn[4];
        if (hb + 4 < HID) {
#pragma unroll
            for (int i = 0; i < 4; i++) wn[i] = wmat[(hb + 4 + i) * 64 + lane];
        }
#pragma unroll
        for (int m = 0; m < 16; m++) {
            float4 a = *(const float4*)(trowbase + m * HID + hb); // LDS broadcast
            acc[m].x += a.x * wreg[0].x + a.y * wreg[1].x + a.z * wreg[2].x + a.w * wreg[3].x;
            acc[m].y += a.x * wreg[0].y + a.y * wreg[1].y + a.z * wreg[2].y + a.w * wreg[3].y;
        }
        if (hb + 4 < HID) {
#pragma unroll
            for (int i = 0; i < 4; i++) wreg[i] = wn[i];
        }
    }
}

// ------- GEMM hop: emb = relu(agg @ W2T + x*w1 + ea*v3); LAST adds W7-head partial -------
template <bool LAST>
__global__ __launch_bounds__(256) void k_gemm(const uint32* __restrict__ agg,  // bf16 [N][64u32]
                                              const float* __restrict__ w2tl,
                                              const float* __restrict__ w1l,
                                              const float* __restrict__ v3l,
                                              const float* __restrict__ x,
                                              const float* __restrict__ ea_sum,
                                              uint32* __restrict__ embOut,
                                              const float* __restrict__ w7t,
                                              const float* __restrict__ W5,
                                              float* __restrict__ outp) {
    __shared__ float tile[64 * HID]; // 32 KB
    int tid = threadIdx.x;
    int tbase = blockIdx.x * 64;
    // stage agg tile: unpack bf16 -> fp32 (uint2 = 4 values per iter)
    {
        const uint2* src = (const uint2*)(agg + (size_t)tbase * 64);
        int vn = N_NODES - tbase; if (vn > 64) vn = 64;
        int lim = vn * 32;
        for (int i = tid; i < 64 * 32; i += 256) {
            uint2 u = (i < lim) ? src[i] : make_uint2(0u, 0u);
            int node = i >> 5, cb = (i & 31) * 4;
            float4 v = {bf_lo(u.x), bf_hi(u.x), bf_lo(u.y), bf_hi(u.y)};
            *(float4*)&tile[node * HID + cb] = v;
        }
    }
    __syncthreads();
    int w = tid >> 6, lane = tid & 63;
    int rowbase = w * 16;
    float2 acc[16];
#pragma unroll
    for (int m = 0; m < 16; m++) acc[m] = {0.f, 0.f};
    gemm16(tile + rowbase * HID, (const float2*)w2tl, lane, acc);

    float2 w1p = ((const float2*)w1l)[lane];
    float2 v3p = ((const float2*)v3l)[lane];
#pragma unroll
    for (int m = 0; m < 16; m++) {
        int n = tbase + rowbase + m;
        float xs = 0.f, es = 0.f;
        if (n < N_NODES) { xs = x[n]; es = ea_sum[n]; }
        float2 r;
        r.x = fmaxf(acc[m].x + xs * w1p.x + es * v3p.x, 0.f);
        r.y = fmaxf(acc[m].y + xs * w1p.y + es * v3p.y, 0.f);
        if (n < N_NODES) embOut[(size_t)n * 64 + lane] = pack_bf16(r.x, r.y);
        if (LAST) {
            *(float2*)&tile[(rowbase + m) * HID + 2 * lane] = r; // wave-private rows
            acc[m] = {0.f, 0.f};
        }
    }
    if (LAST) {
        gemm16(tile + rowbase * HID, (const float2*)w7t, lane, acc);
        float2 w5p = ((const float2*)W5)[64 + lane];
#pragma unroll
        for (int m = 0; m < 16; m++) {
            float p = fmaxf(acc[m].x, 0.f) * w5p.x + fmaxf(acc[m].y, 0.f) * w5p.y;
            for (int off = 32; off > 0; off >>= 1) p += __shfl_down(p, off);
            int n = tbase + rowbase + m;
            if (lane == 0 && n < N_NODES) outp[n] = p;
        }
    }
}

// ---------------- graph pooling over bf16 emb (batch sorted) ----------------
__global__ __launch_bounds__(128) void k_pool(const unsigned short* __restrict__ emb16,
                                              const int* __restrict__ batch,
                                              float* __restrict__ pooled) {
    const int CH = 256;
    int t = threadIdx.x;
    int start = blockIdx.x * CH;
    int end = start + CH; if (end > N_NODES) end = N_NODES;
    if (start >= N_NODES) return;
    float acc = 0.f;
    int cur = batch[start];
    for (int n = start; n < end; n++) {
        int g = batch[n];
        if (g != cur) { atomicAdd(&pooled[cur * HID + t], acc); acc = 0.f; cur = g; }
        acc += __uint_as_float(((uint32)emb16[(size_t)n * HID + t]) << 16);
    }
    atomicAdd(&pooled[cur * HID + t], acc);
}

// ---------------- per-graph scalar: s_g = relu(pooled@W6T) . W5[:128] ----------------
__global__ __launch_bounds__(128) void k_graph(const float* __restrict__ pooled,
                                               const float* __restrict__ W6,
                                               const float* __restrict__ W5,
                                               float* __restrict__ s_g) {
    int g = blockIdx.x, hp = threadIdx.x;
    float acc = 0.f;
    for (int h = 0; h < HID; h++) acc += pooled[g * HID + h] * W6[hp * HID + h];
    float v = fmaxf(acc, 0.f) * W5[hp];
    __shared__ float red[HID];
    red[hp] = v;
    __syncthreads();
    for (int d = 64; d > 0; d >>= 1) {
        if (hp < d) red[hp] += red[hp + d];
        __syncthreads();
    }
    if (hp == 0) s_g[g] = red[0];
}

// ---------------- final add: out[n] += s_g[batch[n]] + b5 ----------------
__global__ __launch_bounds__(256) void k_addsg(float* __restrict__ out,
                                               const int* __restrict__ batch,
                                               const float* __restrict__ s_g,
                                               const float* __restrict__ b5) {
    int n = blockIdx.x * 256 + threadIdx.x;
    if (n < N_NODES) out[n] += s_g[batch[n]] + b5[0];
}

extern "C" void kernel_launch(void* const* d_in, const int* in_sizes, int n_in,
                              void* d_out, int out_size, void* d_ws, size_t ws_size,
                              hipStream_t stream) {
    (void)in_sizes; (void)n_in; (void)out_size; (void)ws_size;
    const float* x    = (const float*)d_in[0];
    const int*   ei   = (const int*)d_in[1];   // [2,E] flat: row then col
    const float* ea   = (const float*)d_in[2];
    const int*   bat  = (const int*)d_in[3];
    const float* W1   = (const float*)d_in[4]; // [3,128,1]
    const float* W2   = (const float*)d_in[5]; // [3,128,128]
    const float* W3   = (const float*)d_in[6];
    const float* W4   = (const float*)d_in[7]; // [3,128,1]
    const float* W5   = (const float*)d_in[8]; // [1,256]
    const float* b5   = (const float*)d_in[9];
    const float* W6   = (const float*)d_in[10];
    const float* W7   = (const float*)d_in[11];
    float* out = (float*)d_out;

    const int* row = ei;
    const int* col = ei + N_EDGES;

    // workspace layout (4B elems)
    float* wsf = (float*)d_ws;
    int*   wsi = (int*)d_ws;
    size_t o = 0;
    float* pooled = wsf + o; o += NGRAPH * HID;     // zeroed (atomic targets)
    float* s_g    = wsf + o; o += NGRAPH;           // zeroed
    size_t ztot = o;
    int*   offs   = wsi + o; o += N_NODES + 1;
    float* ea_sum = wsf + o; o += N_NODES;
    int*   bbase  = wsi + o; o += NB + 1;
    int*   blkh   = wsi + o; o += NB * NBLK;
    float* v3     = wsf + o; o += 3 * HID;
    float* w2t    = wsf + o; o += 3 * HID * HID;
    float* w7t    = wsf + o; o += HID * HID;
    int*    csr    = wsi + o;            o += N_EDGES;
    uint32* packed = (uint32*)(wsi + o); o += N_EDGES;
    float*  eaq    = wsf + o;            o += N_EDGES;
    o = (o + 3) & ~(size_t)3;
    uint32* embA   = (uint32*)(wsi + o); o += (size_t)N_NODES * 64; // bf16 [N][128]
    uint32* embB   = (uint32*)(wsi + o); o += (size_t)N_NODES * 64;
    o = (o + 3) & ~(size_t)3;
    uint32* aggB   = (uint32*)(wsi + o); o += (size_t)N_NODES * 64; // bf16 [N][128]

    // 0) zero atomic accumulators
    k_zero<<<(int)((ztot + 255) / 256), 256, 0, stream>>>((float*)d_ws, (int)ztot);
    // 1) atomic-free CSR build
    k_p1_hist<<<NBLK, 256, 0, stream>>>(row, blkh);
    k_p2_scan<<<1, 512, 0, stream>>>(blkh, bbase);
    k_p3_part<<<NBLK, 256, 0, stream>>>(row, col, ea, blkh, packed, eaq);
    k_p4<<<NB, 256, 0, stream>>>(packed, eaq, bbase, offs, ea_sum, csr);
    // 2) weight precompute
    k_prep<<<(4 * HID * HID + 255) / 256, 256, 0, stream>>>(W2, W7, W3, W4, w2t, w7t, v3);
    // 3) hop 0 -> embA
    k_hop0<<<(N_NODES * 64 + 255) / 256, 256, 0, stream>>>(x, ea_sum, W1, v3, embA);
    // 4) hop 1: gather embA -> aggB ; gemm -> embB
    k_gather<<<(N_NODES * 64 + 255) / 256, 256, 0, stream>>>(embA, offs, csr, aggB);
    k_gemm<false><<<(N_NODES + 63) / 64, 256, 0, stream>>>(
        aggB, w2t + 1 * HID * HID, W1 + 1 * HID, v3 + 1 * HID, x, ea_sum,
        embB, nullptr, nullptr, nullptr);
    // 5) hop 2: gather embB -> aggB ; gemm -> embA + W7 head partial -> out
    k_gather<<<(N_NODES * 64 + 255) / 256, 256, 0, stream>>>(embB, offs, csr, aggB);
    k_gemm<true><<<(N_NODES + 63) / 64, 256, 0, stream>>>(
        aggB, w2t + 2 * HID * HID, W1 + 2 * HID, v3 + 2 * HID, x, ea_sum,
        embA, w7t, W5, out);
    // 6) graph pooling (bf16 emb)
    k_pool<<<(N_NODES + 255) / 256, 128, 0, stream>>>((const unsigned short*)embA, bat, pooled);
    // 7) per-graph scalars
    k_graph<<<NGRAPH, 128, 0, stream>>>(pooled, W6, W5, s_g);
    // 8) add graph term + bias
    k_addsg<<<(N_NODES + 255) / 256, 256, 0, stream>>>(out, bat, s_g, b5);
}

// Round 5
// 367.109 us; speedup vs baseline: 2.6089x; 1.4755x over previous
//
#include <hip/hip_runtime.h>
#include <hip/hip_bf16.h>

#define N_NODES 50000
#define N_EDGES 1600000
#define NGRAPH  16
#define HID     128

#define RPB   128                           // rows per bucket
#define NB    ((N_NODES + RPB - 1) / RPB)   // 391 buckets
#define NBLK  256                           // partition blocks
#define EPB   ((N_EDGES + NBLK - 1) / NBLK) // 6250 edges per partition block

typedef unsigned int uint32;
typedef unsigned short ushort;
typedef __attribute__((ext_vector_type(8))) short bf16x8;
typedef __attribute__((ext_vector_type(4))) float f32x4;

// bf16 round-to-nearest-even helpers
__device__ __forceinline__ uint32 bf16r(float f) {
    uint32 b = __float_as_uint(f);
    return (b + 0x7fffu + ((b >> 16) & 1u)) >> 16;
}
__device__ __forceinline__ uint32 pack_bf16(float lo, float hi) {
    return bf16r(lo) | (bf16r(hi) << 16);
}
__device__ __forceinline__ float bf_lo(uint32 u) { return __uint_as_float(u << 16); }
__device__ __forceinline__ float bf_hi(uint32 u) { return __uint_as_float(u & 0xffff0000u); }

// ---------------- zero init ----------------
__global__ __launch_bounds__(256) void k_zero(float* p, int n) {
    int i = blockIdx.x * 256 + threadIdx.x;
    if (i < n) p[i] = 0.f;
}

// ---------------- P1: per-(bucket,block) histogram ----------------
__global__ __launch_bounds__(1024) void k_p1_hist(const int* __restrict__ row,
                                                  int* __restrict__ blkhist) {
    __shared__ int hist[NB];
    int tid = threadIdx.x, blk = blockIdx.x;
    for (int i = tid; i < NB; i += 1024) hist[i] = 0;
    __syncthreads();
    int s = blk * EPB, e = s + EPB; if (e > N_EDGES) e = N_EDGES;
    for (int i = s + tid; i < e; i += 1024)
        atomicAdd(&hist[row[i] >> 7], 1);
    __syncthreads();
    for (int i = tid; i < NB; i += 1024)
        blkhist[i * NBLK + blk] = hist[i];
}

// ------- P2a: per-bucket exclusive scan over its NBLK per-block counts -------
__global__ __launch_bounds__(NBLK) void k_p2a(int* __restrict__ blkhist,
                                              int* __restrict__ btot) {
    __shared__ int sums[NBLK];
    int t = threadIdx.x, b = blockIdx.x;
    int v = blkhist[b * NBLK + t];
    sums[t] = v;
    __syncthreads();
    for (int d = 1; d < NBLK; d <<= 1) {
        int u = (t >= d) ? sums[t - d] : 0;
        __syncthreads();
        sums[t] += u;
        __syncthreads();
    }
    blkhist[b * NBLK + t] = sums[t] - v;     // local exclusive
    if (t == NBLK - 1) btot[b] = sums[t];    // bucket total
}

// ------- P2b: scan bucket totals -> bucket bases -------
__global__ __launch_bounds__(512) void k_p2b(const int* __restrict__ btot,
                                             int* __restrict__ bbase) {
    __shared__ int sums[512];
    int t = threadIdx.x;
    int s = (t < NB) ? btot[t] : 0;
    sums[t] = s;
    __syncthreads();
    for (int d = 1; d < 512; d <<= 1) {
        int v = (t >= d) ? sums[t - d] : 0;
        __syncthreads();
        sums[t] += v;
        __syncthreads();
    }
    if (t < NB) {
        bbase[t] = sums[t] - s;
        if (t == NB - 1) bbase[NB] = sums[t]; // == E
    }
}

// ------- P3: scatter int2{rowlocal:8|col:16, ea} into bucket runs (LDS cursors) -------
__global__ __launch_bounds__(1024) void k_p3_part(const int* __restrict__ row,
                                                  const int* __restrict__ col,
                                                  const float* __restrict__ ea,
                                                  const int* __restrict__ blkhist,
                                                  const int* __restrict__ bbase,
                                                  int2* __restrict__ pea) {
    __shared__ int cur[NB];
    int tid = threadIdx.x, blk = blockIdx.x;
    for (int i = tid; i < NB; i += 1024)
        cur[i] = bbase[i] + blkhist[i * NBLK + blk];
    __syncthreads();
    int s = blk * EPB, e = s + EPB; if (e > N_EDGES) e = N_EDGES;
    for (int i = s + tid; i < e; i += 1024) {
        int r = row[i], c = col[i];
        float a = ea[i];
        int slot = atomicAdd(&cur[r >> 7], 1);
        pea[slot] = make_int2(((r & (RPB - 1)) << 16) | c, __float_as_int(a));
    }
}

// ------- P4: per-bucket counts + ea_sum + local scan -> offs; then scatter csr -------
__global__ __launch_bounds__(512) void k_p4(const int2* __restrict__ pea,
                                            const int* __restrict__ bbase,
                                            int* __restrict__ offs,
                                            float* __restrict__ ea_sum,
                                            int* __restrict__ csr) {
    __shared__ int   cnt[RPB];
    __shared__ float eas[RPB];
    __shared__ int   scan_s[RPB];
    __shared__ int   cur[RPB];
    int tid = threadIdx.x, b = blockIdx.x;
    if (tid < RPB) { cnt[tid] = 0; eas[tid] = 0.f; }
    __syncthreads();
    int s = bbase[b], e = bbase[b + 1];
    for (int i = s + tid; i < e; i += 512) {
        int2 p = pea[i];
        int lr = ((uint32)p.x) >> 16;
        atomicAdd(&cnt[lr], 1);
        atomicAdd(&eas[lr], __int_as_float(p.y));
    }
    __syncthreads();
    if (tid < RPB) scan_s[tid] = cnt[tid];
    __syncthreads();
    for (int d = 1; d < RPB; d <<= 1) {
        int v = 0;
        if (tid < RPB && tid >= d) v = scan_s[tid - d];
        __syncthreads();
        if (tid < RPB) scan_s[tid] += v;
        __syncthreads();
    }
    int nbase = b * RPB;
    if (tid < RPB) {
        int excl = scan_s[tid] - cnt[tid];
        int n = nbase + tid;
        if (n < N_NODES) { offs[n] = s + excl; ea_sum[n] = eas[tid]; }
        cur[tid] = s + excl;
    }
    if (b == NB - 1 && tid == 0) offs[N_NODES] = e;
    __syncthreads();
    for (int i = s + tid; i < e; i += 512) {
        int2 p = pea[i];
        int slot = atomicAdd(&cur[((uint32)p.x) >> 16], 1);
        csr[slot] = p.x & 0xFFFF;
    }
}

// ------- prep: pack W2 (x3) + W7 into MFMA B-fragment order (bf16); v3 = W3@relu(W4) -------
// B-frag layout per layer: [t:8][kk:4][lane:64][j:8] bf16; entry = W[(t*16+(lane&15))][kk*32+(lane>>4)*8+j]
__global__ __launch_bounds__(256) void k_prep(const float* __restrict__ W2,
                                              const float* __restrict__ W7,
                                              const float* __restrict__ W3,
                                              const float* __restrict__ W4,
                                              ushort* __restrict__ wpack,  // 4 layers x 16384
                                              float* __restrict__ v3) {
    int idx = blockIdx.x * 256 + threadIdx.x;
    if (idx < 4 * 16384) {
        int m = idx >> 14, f = idx & 16383;
        int j = f & 7, lane = (f >> 3) & 63, kk = (f >> 9) & 3, t = (f >> 11) & 7;
        int hp = t * 16 + (lane & 15);
        int k  = kk * 32 + ((lane >> 4) & 3) * 8 + j;
        const float* src = (m < 3) ? (W2 + m * HID * HID) : W7;
        wpack[idx] = (ushort)bf16r(src[hp * HID + k]);
    }
    if (idx < 3 * HID) {
        int l = idx / HID, hp = idx % HID;
        float acc = 0.f;
        for (int h = 0; h < HID; h++)
            acc += W3[l * HID * HID + hp * HID + h] * fmaxf(W4[l * HID + h], 0.f);
        v3[idx] = acc;
    }
}

// ---------------- hop 0: emb(bf16) = relu(x*w1 + ea_sum*v3) ----------------
__global__ __launch_bounds__(256) void k_hop0(const float* __restrict__ x,
                                              const float* __restrict__ ea_sum,
                                              const float* __restrict__ w1,
                                              const float* __restrict__ v3,
                                              uint32* __restrict__ emb) {
    int idx = blockIdx.x * 256 + threadIdx.x; // over N*64
    if (idx < N_NODES * 64) {
        int n = idx >> 6, l = idx & 63;
        float xs = x[n], es = ea_sum[n];
        float r0 = fmaxf(xs * w1[2 * l]     + es * v3[2 * l],     0.f);
        float r1 = fmaxf(xs * w1[2 * l + 1] + es * v3[2 * l + 1], 0.f);
        emb[idx] = pack_bf16(r0, r1);
    }
}

// ------- gather: agg(bf16)[n] = sum over neighbors of emb(bf16)[col] -------
__global__ __launch_bounds__(256) void k_gather(const uint32* __restrict__ emb,
                                                const int* __restrict__ offs,
                                                const int* __restrict__ csr,
                                                uint32* __restrict__ agg) {
    int node = (blockIdx.x * 256 + threadIdx.x) >> 6;
    int lane = threadIdx.x & 63;
    if (node >= N_NODES) return;
    int s = offs[node], e = offs[node + 1];
    float2 a0 = {0.f, 0.f}, a1 = {0.f, 0.f}, a2 = {0.f, 0.f}, a3 = {0.f, 0.f};
    int j = s;
    for (; j + 4 <= e; j += 4) {
        int c0 = csr[j], c1 = csr[j + 1], c2 = csr[j + 2], c3 = csr[j + 3];
        uint32 u0 = emb[(size_t)c0 * 64 + lane];
        uint32 u1 = emb[(size_t)c1 * 64 + lane];
        uint32 u2 = emb[(size_t)c2 * 64 + lane];
        uint32 u3 = emb[(size_t)c3 * 64 + lane];
        a0.x += bf_lo(u0); a0.y += bf_hi(u0);
        a1.x += bf_lo(u1); a1.y += bf_hi(u1);
        a2.x += bf_lo(u2); a2.y += bf_hi(u2);
        a3.x += bf_lo(u3); a3.y += bf_hi(u3);
    }
    for (; j < e; j++) {
        uint32 u = emb[(size_t)csr[j] * 64 + lane];
        a0.x += bf_lo(u); a0.y += bf_hi(u);
    }
    float rx = (a0.x + a1.x) + (a2.x + a3.x);
    float ry = (a0.y + a1.y) + (a2.y + a3.y);
    agg[(size_t)node * 64 + lane] = pack_bf16(rx, ry);
}

#define LROW 136  // padded LDS row, bf16 elems (272 B: 2-way bank aliasing only)

// ------- MFMA GEMM hop: emb = relu(agg @ W2T + x*w1 + ea*v3); LAST fuses W7-head -------
// block = 64 nodes, 4 waves; wave w owns nodes [tbase+16w, tbase+16w+16)
template <bool LAST>
__global__ __launch_bounds__(256) void k_gemm(const uint32* __restrict__ agg,   // bf16 [N][64u32]
                                              const ushort* __restrict__ w2p,   // B-frag packed
                                              const float* __restrict__ w1l,
                                              const float* __restrict__ v3l,
                                              const float* __restrict__ x,
                                              const float* __restrict__ ea_sum,
                                              uint32* __restrict__ embOut,
                                              const ushort* __restrict__ w7p,
                                              const float* __restrict__ W5,
                                              float* __restrict__ outp) {
    __shared__ ushort tile[64 * LROW]; // 17408 B
    int tid = threadIdx.x;
    int tbase = blockIdx.x * 64;
    // stage agg tile (raw bf16) into padded LDS
    {
        const uint2* src = (const uint2*)(agg + (size_t)tbase * 64);
        int vn = N_NODES - tbase; if (vn > 64) vn = 64;
        int lim = vn * 32;
        for (int i = tid; i < 64 * 32; i += 256) {
            uint2 u = (i < lim) ? src[i] : make_uint2(0u, 0u);
            int r = i >> 5, c4 = (i & 31) * 4;
            *(uint2*)&tile[r * LROW + c4] = u;
        }
    }
    __syncthreads();
    int wv = tid >> 6, lane = tid & 63;
    int n0 = lane & 15, quad = lane >> 4;
    int arow = wv * 16 + n0;
    // A fragments (4 k-steps of 32)
    bf16x8 a0 = *(const bf16x8*)&tile[arow * LROW + 0 * 32 + quad * 8];
    bf16x8 a1 = *(const bf16x8*)&tile[arow * LROW + 1 * 32 + quad * 8];
    bf16x8 a2 = *(const bf16x8*)&tile[arow * LROW + 2 * 32 + quad * 8];
    bf16x8 a3 = *(const bf16x8*)&tile[arow * LROW + 3 * 32 + quad * 8];
    const bf16x8* wb = (const bf16x8*)w2p;
    f32x4 acc[8];
#pragma unroll
    for (int t = 0; t < 8; t++) {
        f32x4 c = {0.f, 0.f, 0.f, 0.f};
        c = __builtin_amdgcn_mfma_f32_16x16x32_bf16(a0, wb[(t * 4 + 0) * 64 + lane], c, 0, 0, 0);
        c = __builtin_amdgcn_mfma_f32_16x16x32_bf16(a1, wb[(t * 4 + 1) * 64 + lane], c, 0, 0, 0);
        c = __builtin_amdgcn_mfma_f32_16x16x32_bf16(a2, wb[(t * 4 + 2) * 64 + lane], c, 0, 0, 0);
        c = __builtin_amdgcn_mfma_f32_16x16x32_bf16(a3, wb[(t * 4 + 3) * 64 + lane], c, 0, 0, 0);
        acc[t] = c;
    }
    // epilogue-1: + x*w1 + ea*v3, relu, write bf16 back to LDS tile (wave-private rows)
    float xs[4], es[4];
#pragma unroll
    for (int r = 0; r < 4; r++) {
        int n = tbase + wv * 16 + quad * 4 + r;
        xs[r] = (n < N_NODES) ? x[n] : 0.f;
        es[r] = (n < N_NODES) ? ea_sum[n] : 0.f;
    }
#pragma unroll
    for (int t = 0; t < 8; t++) {
        int hp = t * 16 + n0;
        float w1v = w1l[hp], v3v = v3l[hp];
#pragma unroll
        for (int r = 0; r < 4; r++) {
            float v = fmaxf(acc[t][r] + xs[r] * w1v + es[r] * v3v, 0.f);
            tile[(wv * 16 + quad * 4 + r) * LROW + hp] = (ushort)bf16r(v);
        }
    }
    __syncthreads();
    // store emb from LDS (coalesced uint2)
    {
        int vn = N_NODES - tbase; if (vn > 64) vn = 64;
        for (int i = tid; i < 64 * 32; i += 256) {
            int r = i >> 5, c4 = (i & 31) * 4;
            if (r < vn) {
                uint2 u = *(const uint2*)&tile[r * LROW + c4];
                *(uint2*)(embOut + (size_t)(tbase + r) * 64 + (size_t)(i & 31) * 2) = u;
            }
        }
    }
    if (LAST) {
        // W7-head: relu(emb @ W7T) . W5[128:]
        bf16x8 b0 = *(const bf16x8*)&tile[arow * LROW + 0 * 32 + quad * 8];
        bf16x8 b1 = *(const bf16x8*)&tile[arow * LROW + 1 * 32 + quad * 8];
        bf16x8 b2 = *(const bf16x8*)&tile[arow * LROW + 2 * 32 + quad * 8];
        bf16x8 b3 = *(const bf16x8*)&tile[arow * LROW + 3 * 32 + quad * 8];
        const bf16x8* w7 = (const bf16x8*)w7p;
        float p[4] = {0.f, 0.f, 0.f, 0.f};
#pragma unroll
        for (int t = 0; t < 8; t++) {
            f32x4 c = {0.f, 0.f, 0.f, 0.f};
            c = __builtin_amdgcn_mfma_f32_16x16x32_bf16(b0, w7[(t * 4 + 0) * 64 + lane], c, 0, 0, 0);
            c = __builtin_amdgcn_mfma_f32_16x16x32_bf16(b1, w7[(t * 4 + 1) * 64 + lane], c, 0, 0, 0);
            c = __builtin_amdgcn_mfma_f32_16x16x32_bf16(b2, w7[(t * 4 + 2) * 64 + lane], c, 0, 0, 0);
            c = __builtin_amdgcn_mfma_f32_16x16x32_bf16(b3, w7[(t * 4 + 3) * 64 + lane], c, 0, 0, 0);
            float w5v = W5[128 + t * 16 + n0];
#pragma unroll
            for (int r = 0; r < 4; r++) p[r] += fmaxf(c[r], 0.f) * w5v;
        }
#pragma unroll
        for (int r = 0; r < 4; r++) {
            float v = p[r];
            v += __shfl_xor(v, 1);
            v += __shfl_xor(v, 2);
            v += __shfl_xor(v, 4);
            v += __shfl_xor(v, 8);
            int n = tbase + wv * 16 + quad * 4 + r;
            if (n0 == 0 && n < N_NODES) outp[n] = v;
        }
    }
}

// ---------------- graph pooling over bf16 emb (batch sorted) ----------------
__global__ __launch_bounds__(128) void k_pool(const ushort* __restrict__ emb16,
                                              const int* __restrict__ batch,
                                              float* __restrict__ pooled) {
    const int CH = 256;
    int t = threadIdx.x;
    int start = blockIdx.x * CH;
    int end = start + CH; if (end > N_NODES) end = N_NODES;
    if (start >= N_NODES) return;
    float acc = 0.f;
    int cur = batch[start];
    for (int n = start; n < end; n++) {
        int g = batch[n];
        if (g != cur) { atomicAdd(&pooled[cur * HID + t], acc); acc = 0.f; cur = g; }
        acc += __uint_as_float(((uint32)emb16[(size_t)n * HID + t]) << 16);
    }
    atomicAdd(&pooled[cur * HID + t], acc);
}

// ---------------- per-graph scalar: s_g = relu(pooled@W6T) . W5[:128] ----------------
__global__ __launch_bounds__(128) void k_graph(const float* __restrict__ pooled,
                                               const float* __restrict__ W6,
                                               const float* __restrict__ W5,
                                               float* __restrict__ s_g) {
    int g = blockIdx.x, hp = threadIdx.x;
    float acc = 0.f;
    for (int h = 0; h < HID; h++) acc += pooled[g * HID + h] * W6[hp * HID + h];
    float v = fmaxf(acc, 0.f) * W5[hp];
    __shared__ float red[HID];
    red[hp] = v;
    __syncthreads();
    for (int d = 64; d > 0; d >>= 1) {
        if (hp < d) red[hp] += red[hp + d];
        __syncthreads();
    }
    if (hp == 0) s_g[g] = red[0];
}

// ---------------- final add: out[n] += s_g[batch[n]] + b5 ----------------
__global__ __launch_bounds__(256) void k_addsg(float* __restrict__ out,
                                               const int* __restrict__ batch,
                                               const float* __restrict__ s_g,
                                               const float* __restrict__ b5) {
    int n = blockIdx.x * 256 + threadIdx.x;
    if (n < N_NODES) out[n] += s_g[batch[n]] + b5[0];
}

extern "C" void kernel_launch(void* const* d_in, const int* in_sizes, int n_in,
                              void* d_out, int out_size, void* d_ws, size_t ws_size,
                              hipStream_t stream) {
    (void)in_sizes; (void)n_in; (void)out_size; (void)ws_size;
    const float* x    = (const float*)d_in[0];
    const int*   ei   = (const int*)d_in[1];   // [2,E] flat: row then col
    const float* ea   = (const float*)d_in[2];
    const int*   bat  = (const int*)d_in[3];
    const float* W1   = (const float*)d_in[4]; // [3,128,1]
    const float* W2   = (const float*)d_in[5]; // [3,128,128]
    const float* W3   = (const float*)d_in[6];
    const float* W4   = (const float*)d_in[7]; // [3,128,1]
    const float* W5   = (const float*)d_in[8]; // [1,256]
    const float* b5   = (const float*)d_in[9];
    const float* W6   = (const float*)d_in[10];
    const float* W7   = (const float*)d_in[11];
    float* out = (float*)d_out;

    const int* row = ei;
    const int* col = ei + N_EDGES;

    // workspace layout (4B elems)
    float* wsf = (float*)d_ws;
    int*   wsi = (int*)d_ws;
    size_t o = 0;
    float* pooled = wsf + o; o += NGRAPH * HID;     // zeroed (atomic targets)
    float* s_g    = wsf + o; o += NGRAPH;           // zeroed
    size_t ztot = o;
    int*   offs   = wsi + o; o += N_NODES + 1;
    float* ea_sum = wsf + o; o += N_NODES;
    int*   btot   = wsi + o; o += NB;
    int*   bbase  = wsi + o; o += NB + 1;
    float* v3     = wsf + o; o += 3 * HID;
    int*   blkh   = wsi + o; o += NB * NBLK;        // 100096
    o = (o + 3) & ~(size_t)3;
    ushort* wpack = (ushort*)(wsi + o); o += 4 * 16384 / 2;  // 4 layers B-frag packed
    int*    csr   = wsi + o; o += N_EDGES;
    o = (o + 1) & ~(size_t)1;
    int2*   pea   = (int2*)(wsi + o); o += 2 * (size_t)N_EDGES;
    o = (o + 1) & ~(size_t)1;
    uint32* embA  = (uint32*)(wsi + o); o += (size_t)N_NODES * 64; // bf16 [N][128]
    uint32* embB  = (uint32*)(wsi + o); o += (size_t)N_NODES * 64;
    uint32* aggB  = (uint32*)(wsi + o); o += (size_t)N_NODES * 64;

    const ushort* w2p1 = wpack + 1 * 16384;
    const ushort* w2p2 = wpack + 2 * 16384;
    const ushort* w7p  = wpack + 3 * 16384;

    // 0) zero atomic accumulators
    k_zero<<<(int)((ztot + 255) / 256), 256, 0, stream>>>((float*)d_ws, (int)ztot);
    // 1) atomic-free CSR build (highly parallel)
    k_p1_hist<<<NBLK, 1024, 0, stream>>>(row, blkh);
    k_p2a<<<NB, NBLK, 0, stream>>>(blkh, btot);
    k_p2b<<<1, 512, 0, stream>>>(btot, bbase);
    k_p3_part<<<NBLK, 1024, 0, stream>>>(row, col, ea, blkh, bbase, pea);
    k_p4<<<NB, 512, 0, stream>>>(pea, bbase, offs, ea_sum, csr);
    // 2) weight prep: MFMA B-frag packs + v3
    k_prep<<<(4 * 16384 + 255) / 256, 256, 0, stream>>>(W2, W7, W3, W4, (ushort*)wpack, v3);
    // 3) hop 0 -> embA
    k_hop0<<<(N_NODES * 64 + 255) / 256, 256, 0, stream>>>(x, ea_sum, W1, v3, embA);
    // 4) hop 1: gather embA -> aggB ; MFMA gemm -> embB
    k_gather<<<(N_NODES * 64 + 255) / 256, 256, 0, stream>>>(embA, offs, csr, aggB);
    k_gemm<false><<<(N_NODES + 63) / 64, 256, 0, stream>>>(
        aggB, w2p1, W1 + 1 * HID, v3 + 1 * HID, x, ea_sum, embB, nullptr, nullptr, nullptr);
    // 5) hop 2: gather embB -> aggB ; MFMA gemm + W7 head -> embA, out partial
    k_gather<<<(N_NODES * 64 + 255) / 256, 256, 0, stream>>>(embB, offs, csr, aggB);
    k_gemm<true><<<(N_NODES + 63) / 64, 256, 0, stream>>>(
        aggB, w2p2, W1 + 2 * HID, v3 + 2 * HID, x, ea_sum, embA, w7p, W5, out);
    // 6) graph pooling (bf16 emb)
    k_pool<<<(N_NODES + 255) / 256, 128, 0, stream>>>((const ushort*)embA, bat, pooled);
    // 7) per-graph scalars
    k_graph<<<NGRAPH, 128, 0, stream>>>(pooled, W6, W5, s_g);
    // 8) add graph term + bias
    k_addsg<<<(N_NODES + 255) / 256, 256, 0, stream>>>(out, bat, s_g, b5);
}

// Round 6
// 323.352 us; speedup vs baseline: 2.9619x; 1.1353x over previous
//
#include <hip/hip_runtime.h>
#include <hip/hip_bf16.h>

#define N_NODES 50000
#define N_EDGES 1600000
#define NGRAPH  16
#define HID     128

#define RPB   128                           // rows per bucket
#define NB    ((N_NODES + RPB - 1) / RPB)   // 391 buckets
#define NBLK  256                           // partition blocks
#define EPB   ((N_EDGES + NBLK - 1) / NBLK) // 6250 edges per partition block

typedef unsigned int uint32;
typedef unsigned short ushort;
typedef __attribute__((ext_vector_type(8))) short bf16x8;
typedef __attribute__((ext_vector_type(4))) float f32x4;

// bf16 round-to-nearest-even helpers
__device__ __forceinline__ uint32 bf16r(float f) {
    uint32 b = __float_as_uint(f);
    return (b + 0x7fffu + ((b >> 16) & 1u)) >> 16;
}
__device__ __forceinline__ uint32 pack_bf16(float lo, float hi) {
    return bf16r(lo) | (bf16r(hi) << 16);
}
__device__ __forceinline__ float bf_lo(uint32 u) { return __uint_as_float(u << 16); }
__device__ __forceinline__ float bf_hi(uint32 u) { return __uint_as_float(u & 0xffff0000u); }

// ---------------- zero init ----------------
__global__ __launch_bounds__(256) void k_zero(float* p, int n) {
    int i = blockIdx.x * 256 + threadIdx.x;
    if (i < n) p[i] = 0.f;
}

// ---------------- graph boundaries: gstart[g] = lower_bound(batch, g) ----------------
__global__ __launch_bounds__(64) void k_bnd(const int* __restrict__ batch,
                                            int* __restrict__ gstart) {
    int g = threadIdx.x;
    if (g > NGRAPH) return;
    int lo = 0, hi = N_NODES;
    while (lo < hi) {
        int mid = (lo + hi) >> 1;
        if (batch[mid] < g) lo = mid + 1; else hi = mid;
    }
    gstart[g] = lo;
}

// ---------------- P1: per-(bucket,block) histogram ----------------
__global__ __launch_bounds__(1024) void k_p1_hist(const int* __restrict__ row,
                                                  int* __restrict__ blkhist) {
    __shared__ int hist[NB];
    int tid = threadIdx.x, blk = blockIdx.x;
    for (int i = tid; i < NB; i += 1024) hist[i] = 0;
    __syncthreads();
    int s = blk * EPB, e = s + EPB; if (e > N_EDGES) e = N_EDGES;
    for (int i = s + tid; i < e; i += 1024)
        atomicAdd(&hist[row[i] >> 7], 1);
    __syncthreads();
    for (int i = tid; i < NB; i += 1024)
        blkhist[i * NBLK + blk] = hist[i];
}

// ------- P2a: per-bucket exclusive scan over its NBLK per-block counts -------
__global__ __launch_bounds__(NBLK) void k_p2a(int* __restrict__ blkhist,
                                              int* __restrict__ btot) {
    __shared__ int sums[NBLK];
    int t = threadIdx.x, b = blockIdx.x;
    int v = blkhist[b * NBLK + t];
    sums[t] = v;
    __syncthreads();
    for (int d = 1; d < NBLK; d <<= 1) {
        int u = (t >= d) ? sums[t - d] : 0;
        __syncthreads();
        sums[t] += u;
        __syncthreads();
    }
    blkhist[b * NBLK + t] = sums[t] - v;     // local exclusive
    if (t == NBLK - 1) btot[b] = sums[t];    // bucket total
}

// ------- P2b: scan bucket totals -> bucket bases -------
__global__ __launch_bounds__(512) void k_p2b(const int* __restrict__ btot,
                                             int* __restrict__ bbase) {
    __shared__ int sums[512];
    int t = threadIdx.x;
    int s = (t < NB) ? btot[t] : 0;
    sums[t] = s;
    __syncthreads();
    for (int d = 1; d < 512; d <<= 1) {
        int v = (t >= d) ? sums[t - d] : 0;
        __syncthreads();
        sums[t] += v;
        __syncthreads();
    }
    if (t < NB) {
        bbase[t] = sums[t] - s;
        if (t == NB - 1) bbase[NB] = sums[t]; // == E
    }
}

// ------- P3: scatter int2{rowlocal:8|col:16, ea} into bucket runs (LDS cursors) -------
__global__ __launch_bounds__(1024) void k_p3_part(const int* __restrict__ row,
                                                  const int* __restrict__ col,
                                                  const float* __restrict__ ea,
                                                  const int* __restrict__ blkhist,
                                                  const int* __restrict__ bbase,
                                                  int2* __restrict__ pea) {
    __shared__ int cur[NB];
    int tid = threadIdx.x, blk = blockIdx.x;
    for (int i = tid; i < NB; i += 1024)
        cur[i] = bbase[i] + blkhist[i * NBLK + blk];
    __syncthreads();
    int s = blk * EPB, e = s + EPB; if (e > N_EDGES) e = N_EDGES;
    for (int i = s + tid; i < e; i += 1024) {
        int r = row[i], c = col[i];
        float a = ea[i];
        int slot = atomicAdd(&cur[r >> 7], 1);
        pea[slot] = make_int2(((r & (RPB - 1)) << 16) | c, __float_as_int(a));
    }
}

// ------- P4: per-bucket counts + ea_sum + local scan -> offs; scatter csr; write pxe -------
__global__ __launch_bounds__(512) void k_p4(const int2* __restrict__ pea,
                                            const int* __restrict__ bbase,
                                            const float* __restrict__ x,
                                            int* __restrict__ offs,
                                            float* __restrict__ ea_sum,
                                            float2* __restrict__ pxe,
                                            int* __restrict__ csr) {
    __shared__ int   cnt[RPB];
    __shared__ float eas[RPB];
    __shared__ int   scan_s[RPB];
    __shared__ int   cur[RPB];
    int tid = threadIdx.x, b = blockIdx.x;
    if (tid < RPB) { cnt[tid] = 0; eas[tid] = 0.f; }
    __syncthreads();
    int s = bbase[b], e = bbase[b + 1];
    for (int i = s + tid; i < e; i += 512) {
        int2 p = pea[i];
        int lr = ((uint32)p.x) >> 16;
        atomicAdd(&cnt[lr], 1);
        atomicAdd(&eas[lr], __int_as_float(p.y));
    }
    __syncthreads();
    if (tid < RPB) scan_s[tid] = cnt[tid];
    __syncthreads();
    for (int d = 1; d < RPB; d <<= 1) {
        int v = 0;
        if (tid < RPB && tid >= d) v = scan_s[tid - d];
        __syncthreads();
        if (tid < RPB) scan_s[tid] += v;
        __syncthreads();
    }
    int nbase = b * RPB;
    if (tid < RPB) {
        int excl = scan_s[tid] - cnt[tid];
        int n = nbase + tid;
        if (n < N_NODES) {
            offs[n] = s + excl;
            ea_sum[n] = eas[tid];
            pxe[n] = make_float2(x[n], eas[tid]);
        }
        cur[tid] = s + excl;
    }
    if (b == NB - 1 && tid == 0) offs[N_NODES] = e;
    __syncthreads();
    for (int i = s + tid; i < e; i += 512) {
        int2 p = pea[i];
        int slot = atomicAdd(&cur[((uint32)p.x) >> 16], 1);
        csr[slot] = p.x & 0xFFFF;
    }
}

// ------- prep: pack W2 (x3) + W7 into MFMA B-fragment order (bf16); v3 = W3@relu(W4) -------
__global__ __launch_bounds__(256) void k_prep(const float* __restrict__ W2,
                                              const float* __restrict__ W7,
                                              const float* __restrict__ W3,
                                              const float* __restrict__ W4,
                                              ushort* __restrict__ wpack,  // 4 layers x 16384
                                              float* __restrict__ v3) {
    int idx = blockIdx.x * 256 + threadIdx.x;
    if (idx < 4 * 16384) {
        int m = idx >> 14, f = idx & 16383;
        int j = f & 7, lane = (f >> 3) & 63, kk = (f >> 9) & 3, t = (f >> 11) & 7;
        int hp = t * 16 + (lane & 15);
        int k  = kk * 32 + ((lane >> 4) & 3) * 8 + j;
        const float* src = (m < 3) ? (W2 + m * HID * HID) : W7;
        wpack[idx] = (ushort)bf16r(src[hp * HID + k]);
    }
    if (idx < 3 * HID) {
        int l = idx / HID, hp = idx % HID;
        float acc = 0.f;
        for (int h = 0; h < HID; h++)
            acc += W3[l * HID * HID + hp * HID + h] * fmaxf(W4[l * HID + h], 0.f);
        v3[idx] = acc;
    }
}

// ------- hop-1 gather by recompute: agg[n] = sum_c relu(x_c*w1 + es_c*v3), bf16 out -------
// emb0 is a 2-parameter family -> read 8 B/edge instead of 256 B/edge
__global__ __launch_bounds__(256) void k_gather1(const float2* __restrict__ pxe,
                                                 const int* __restrict__ offs,
                                                 const int* __restrict__ csr,
                                                 const float* __restrict__ w1,
                                                 const float* __restrict__ v3,
                                                 uint32* __restrict__ agg) {
    int node = (blockIdx.x * 256 + threadIdx.x) >> 6;
    int lane = threadIdx.x & 63;
    if (node >= N_NODES) return;
    float w1a = w1[2 * lane], w1b = w1[2 * lane + 1];
    float v3a = v3[2 * lane], v3b = v3[2 * lane + 1];
    int s = offs[node], e = offs[node + 1];
    float a0 = 0.f, b0 = 0.f, a1 = 0.f, b1 = 0.f, a2 = 0.f, b2 = 0.f, a3 = 0.f, b3 = 0.f;
    int j = s;
    for (; j + 4 <= e; j += 4) {
        int c0 = csr[j], c1 = csr[j + 1], c2 = csr[j + 2], c3 = csr[j + 3];
        float2 p0 = pxe[c0], p1 = pxe[c1], p2 = pxe[c2], p3 = pxe[c3];
        a0 += fmaxf(p0.x * w1a + p0.y * v3a, 0.f); b0 += fmaxf(p0.x * w1b + p0.y * v3b, 0.f);
        a1 += fmaxf(p1.x * w1a + p1.y * v3a, 0.f); b1 += fmaxf(p1.x * w1b + p1.y * v3b, 0.f);
        a2 += fmaxf(p2.x * w1a + p2.y * v3a, 0.f); b2 += fmaxf(p2.x * w1b + p2.y * v3b, 0.f);
        a3 += fmaxf(p3.x * w1a + p3.y * v3a, 0.f); b3 += fmaxf(p3.x * w1b + p3.y * v3b, 0.f);
    }
    for (; j < e; j++) {
        float2 p = pxe[csr[j]];
        a0 += fmaxf(p.x * w1a + p.y * v3a, 0.f); b0 += fmaxf(p.x * w1b + p.y * v3b, 0.f);
    }
    float rx = (a0 + a1) + (a2 + a3);
    float ry = (b0 + b1) + (b2 + b3);
    agg[(size_t)node * 64 + lane] = pack_bf16(rx, ry);
}

// ------- hop-2 gather: agg(bf16)[n] = sum over neighbors of emb(bf16)[col]; 8-wide -------
__global__ __launch_bounds__(256) void k_gather(const uint32* __restrict__ emb,
                                                const int* __restrict__ offs,
                                                const int* __restrict__ csr,
                                                uint32* __restrict__ agg) {
    int node = (blockIdx.x * 256 + threadIdx.x) >> 6;
    int lane = threadIdx.x & 63;
    if (node >= N_NODES) return;
    int s = offs[node], e = offs[node + 1];
    float ax[8] = {0.f}, ay[8] = {0.f};
    int j = s;
    for (; j + 8 <= e; j += 8) {
        int c[8];
#pragma unroll
        for (int u = 0; u < 8; u++) c[u] = csr[j + u];
        uint32 v[8];
#pragma unroll
        for (int u = 0; u < 8; u++) v[u] = emb[(size_t)c[u] * 64 + lane];
#pragma unroll
        for (int u = 0; u < 8; u++) { ax[u] += bf_lo(v[u]); ay[u] += bf_hi(v[u]); }
    }
    for (; j < e; j++) {
        uint32 u = emb[(size_t)csr[j] * 64 + lane];
        ax[0] += bf_lo(u); ay[0] += bf_hi(u);
    }
    float rx = ((ax[0] + ax[1]) + (ax[2] + ax[3])) + ((ax[4] + ax[5]) + (ax[6] + ax[7]));
    float ry = ((ay[0] + ay[1]) + (ay[2] + ay[3])) + ((ay[4] + ay[5]) + (ay[6] + ay[7]));
    agg[(size_t)node * 64 + lane] = pack_bf16(rx, ry);
}

#define LROW 136  // padded LDS row, bf16 elems

// ------- MFMA GEMM hop: emb = relu(agg @ W2T + x*w1 + ea*v3); LAST fuses W7-head -------
template <bool LAST>
__global__ __launch_bounds__(256) void k_gemm(const uint32* __restrict__ agg,   // bf16 [N][64u32]
                                              const ushort* __restrict__ w2p,   // B-frag packed
                                              const float* __restrict__ w1l,
                                              const float* __restrict__ v3l,
                                              const float* __restrict__ x,
                                              const float* __restrict__ ea_sum,
                                              uint32* __restrict__ embOut,
                                              const ushort* __restrict__ w7p,
                                              const float* __restrict__ W5,
                                              float* __restrict__ outp) {
    __shared__ ushort tile[64 * LROW]; // 17408 B
    int tid = threadIdx.x;
    int tbase = blockIdx.x * 64;
    {
        const uint2* src = (const uint2*)(agg + (size_t)tbase * 64);
        int vn = N_NODES - tbase; if (vn > 64) vn = 64;
        int lim = vn * 32;
        for (int i = tid; i < 64 * 32; i += 256) {
            uint2 u = (i < lim) ? src[i] : make_uint2(0u, 0u);
            int r = i >> 5, c4 = (i & 31) * 4;
            *(uint2*)&tile[r * LROW + c4] = u;
        }
    }
    __syncthreads();
    int wv = tid >> 6, lane = tid & 63;
    int n0 = lane & 15, quad = lane >> 4;
    int arow = wv * 16 + n0;
    bf16x8 a0 = *(const bf16x8*)&tile[arow * LROW + 0 * 32 + quad * 8];
    bf16x8 a1 = *(const bf16x8*)&tile[arow * LROW + 1 * 32 + quad * 8];
    bf16x8 a2 = *(const bf16x8*)&tile[arow * LROW + 2 * 32 + quad * 8];
    bf16x8 a3 = *(const bf16x8*)&tile[arow * LROW + 3 * 32 + quad * 8];
    const bf16x8* wb = (const bf16x8*)w2p;
    f32x4 acc[8];
#pragma unroll
    for (int t = 0; t < 8; t++) {
        f32x4 c = {0.f, 0.f, 0.f, 0.f};
        c = __builtin_amdgcn_mfma_f32_16x16x32_bf16(a0, wb[(t * 4 + 0) * 64 + lane], c, 0, 0, 0);
        c = __builtin_amdgcn_mfma_f32_16x16x32_bf16(a1, wb[(t * 4 + 1) * 64 + lane], c, 0, 0, 0);
        c = __builtin_amdgcn_mfma_f32_16x16x32_bf16(a2, wb[(t * 4 + 2) * 64 + lane], c, 0, 0, 0);
        c = __builtin_amdgcn_mfma_f32_16x16x32_bf16(a3, wb[(t * 4 + 3) * 64 + lane], c, 0, 0, 0);
        acc[t] = c;
    }
    float xs[4], es[4];
#pragma unroll
    for (int r = 0; r < 4; r++) {
        int n = tbase + wv * 16 + quad * 4 + r;
        xs[r] = (n < N_NODES) ? x[n] : 0.f;
        es[r] = (n < N_NODES) ? ea_sum[n] : 0.f;
    }
#pragma unroll
    for (int t = 0; t < 8; t++) {
        int hp = t * 16 + n0;
        float w1v = w1l[hp], v3v = v3l[hp];
#pragma unroll
        for (int r = 0; r < 4; r++) {
            float v = fmaxf(acc[t][r] + xs[r] * w1v + es[r] * v3v, 0.f);
            tile[(wv * 16 + quad * 4 + r) * LROW + hp] = (ushort)bf16r(v);
        }
    }
    __syncthreads();
    {
        int vn = N_NODES - tbase; if (vn > 64) vn = 64;
        for (int i = tid; i < 64 * 32; i += 256) {
            int r = i >> 5, c4 = (i & 31) * 4;
            if (r < vn) {
                uint2 u = *(const uint2*)&tile[r * LROW + c4];
                *(uint2*)(embOut + (size_t)(tbase + r) * 64 + (size_t)(i & 31) * 2) = u;
            }
        }
    }
    if (LAST) {
        bf16x8 b0 = *(const bf16x8*)&tile[arow * LROW + 0 * 32 + quad * 8];
        bf16x8 b1 = *(const bf16x8*)&tile[arow * LROW + 1 * 32 + quad * 8];
        bf16x8 b2 = *(const bf16x8*)&tile[arow * LROW + 2 * 32 + quad * 8];
        bf16x8 b3 = *(const bf16x8*)&tile[arow * LROW + 3 * 32 + quad * 8];
        const bf16x8* w7 = (const bf16x8*)w7p;
        float p[4] = {0.f, 0.f, 0.f, 0.f};
#pragma unroll
        for (int t = 0; t < 8; t++) {
            f32x4 c = {0.f, 0.f, 0.f, 0.f};
            c = __builtin_amdgcn_mfma_f32_16x16x32_bf16(b0, w7[(t * 4 + 0) * 64 + lane], c, 0, 0, 0);
            c = __builtin_amdgcn_mfma_f32_16x16x32_bf16(b1, w7[(t * 4 + 1) * 64 + lane], c, 0, 0, 0);
            c = __builtin_amdgcn_mfma_f32_16x16x32_bf16(b2, w7[(t * 4 + 2) * 64 + lane], c, 0, 0, 0);
            c = __builtin_amdgcn_mfma_f32_16x16x32_bf16(b3, w7[(t * 4 + 3) * 64 + lane], c, 0, 0, 0);
            float w5v = W5[128 + t * 16 + n0];
#pragma unroll
            for (int r = 0; r < 4; r++) p[r] += fmaxf(c[r], 0.f) * w5v;
        }
#pragma unroll
        for (int r = 0; r < 4; r++) {
            float v = p[r];
            v += __shfl_xor(v, 1);
            v += __shfl_xor(v, 2);
            v += __shfl_xor(v, 4);
            v += __shfl_xor(v, 8);
            int n = tbase + wv * 16 + quad * 4 + r;
            if (n0 == 0 && n < N_NODES) outp[n] = v;
        }
    }
}

// ------- pooling: 16 graphs x 16 chunks, branch-free, 4-node ILP -------
__global__ __launch_bounds__(256) void k_pool2(const uint32* __restrict__ emb,
                                               const int* __restrict__ gstart,
                                               float* __restrict__ pooled) {
    __shared__ float2 red[4][64];
    int bid = blockIdx.x;
    int g = bid >> 4, chunk = bid & 15;
    int gs = gstart[g], ge = gstart[g + 1];
    int len = ge - gs;
    int cs = gs + (int)(((long long)len * chunk) >> 4);
    int ce = gs + (int)(((long long)len * (chunk + 1)) >> 4);
    int sub = threadIdx.x >> 6, lane = threadIdx.x & 63;
    float ax = 0.f, ay = 0.f;
    for (int n = cs + sub; n < ce; n += 4) {
        uint32 u = emb[(size_t)n * 64 + lane];
        ax += bf_lo(u); ay += bf_hi(u);
    }
    red[sub][lane] = make_float2(ax, ay);
    __syncthreads();
    if (sub == 0) {
        float2 r0 = red[0][lane], r1 = red[1][lane], r2 = red[2][lane], r3 = red[3][lane];
        atomicAdd(&pooled[g * HID + 2 * lane],     (r0.x + r1.x) + (r2.x + r3.x));
        atomicAdd(&pooled[g * HID + 2 * lane + 1], (r0.y + r1.y) + (r2.y + r3.y));
    }
}

// ---------------- per-graph scalar: s_g = relu(pooled@W6T) . W5[:128] ----------------
__global__ __launch_bounds__(128) void k_graph(const float* __restrict__ pooled,
                                               const float* __restrict__ W6,
                                               const float* __restrict__ W5,
                                               float* __restrict__ s_g) {
    int g = blockIdx.x, hp = threadIdx.x;
    float acc = 0.f;
    for (int h = 0; h < HID; h++) acc += pooled[g * HID + h] * W6[hp * HID + h];
    float v = fmaxf(acc, 0.f) * W5[hp];
    __shared__ float red[HID];
    red[hp] = v;
    __syncthreads();
    for (int d = 64; d > 0; d >>= 1) {
        if (hp < d) red[hp] += red[hp + d];
        __syncthreads();
    }
    if (hp == 0) s_g[g] = red[0];
}

// ---------------- final add: out[n] += s_g[batch[n]] + b5 ----------------
__global__ __launch_bounds__(256) void k_addsg(float* __restrict__ out,
                                               const int* __restrict__ batch,
                                               const float* __restrict__ s_g,
                                               const float* __restrict__ b5) {
    int n = blockIdx.x * 256 + threadIdx.x;
    if (n < N_NODES) out[n] += s_g[batch[n]] + b5[0];
}

extern "C" void kernel_launch(void* const* d_in, const int* in_sizes, int n_in,
                              void* d_out, int out_size, void* d_ws, size_t ws_size,
                              hipStream_t stream) {
    (void)in_sizes; (void)n_in; (void)out_size; (void)ws_size;
    const float* x    = (const float*)d_in[0];
    const int*   ei   = (const int*)d_in[1];   // [2,E] flat: row then col
    const float* ea   = (const float*)d_in[2];
    const int*   bat  = (const int*)d_in[3];
    const float* W1   = (const float*)d_in[4]; // [3,128,1]
    const float* W2   = (const float*)d_in[5]; // [3,128,128]
    const float* W3   = (const float*)d_in[6];
    const float* W4   = (const float*)d_in[7]; // [3,128,1]
    const float* W5   = (const float*)d_in[8]; // [1,256]
    const float* b5   = (const float*)d_in[9];
    const float* W6   = (const float*)d_in[10];
    const float* W7   = (const float*)d_in[11];
    float* out = (float*)d_out;

    const int* row = ei;
    const int* col = ei + N_EDGES;

    // workspace layout (4B elems)
    float* wsf = (float*)d_ws;
    int*   wsi = (int*)d_ws;
    size_t o = 0;
    float* pooled = wsf + o; o += NGRAPH * HID;     // zeroed (atomic targets)
    float* s_g    = wsf + o; o += NGRAPH;           // zeroed
    size_t ztot = o;
    int*   offs   = wsi + o; o += N_NODES + 1;
    float* ea_sum = wsf + o; o += N_NODES;
    int*   gstart = wsi + o; o += NGRAPH + 1;
    int*   btot   = wsi + o; o += NB;
    int*   bbase  = wsi + o; o += NB + 1;
    float* v3     = wsf + o; o += 3 * HID;
    int*   blkh   = wsi + o; o += NB * NBLK;
    o = (o + 1) & ~(size_t)1;
    float2* pxe   = (float2*)(wsi + o); o += 2 * (size_t)N_NODES;
    o = (o + 3) & ~(size_t)3;
    ushort* wpack = (ushort*)(wsi + o); o += 4 * 16384 / 2;
    int*    csr   = wsi + o; o += N_EDGES;
    o = (o + 1) & ~(size_t)1;
    int2*   pea   = (int2*)(wsi + o); o += 2 * (size_t)N_EDGES;
    o = (o + 1) & ~(size_t)1;
    uint32* embA  = (uint32*)(wsi + o); o += (size_t)N_NODES * 64; // bf16 [N][128]
    uint32* embB  = (uint32*)(wsi + o); o += (size_t)N_NODES * 64;
    uint32* aggB  = (uint32*)(wsi + o); o += (size_t)N_NODES * 64;

    const ushort* w2p1 = wpack + 1 * 16384;
    const ushort* w2p2 = wpack + 2 * 16384;
    const ushort* w7p  = wpack + 3 * 16384;

    // 0) zero atomic accumulators + graph boundaries
    k_zero<<<(int)((ztot + 255) / 256), 256, 0, stream>>>((float*)d_ws, (int)ztot);
    k_bnd<<<1, 64, 0, stream>>>(bat, gstart);
    // 1) atomic-free CSR build
    k_p1_hist<<<NBLK, 1024, 0, stream>>>(row, blkh);
    k_p2a<<<NB, NBLK, 0, stream>>>(blkh, btot);
    k_p2b<<<1, 512, 0, stream>>>(btot, bbase);
    k_p3_part<<<NBLK, 1024, 0, stream>>>(row, col, ea, blkh, bbase, pea);
    k_p4<<<NB, 512, 0, stream>>>(pea, bbase, x, offs, ea_sum, pxe, csr);
    // 2) weight prep: MFMA B-frag packs + v3
    k_prep<<<(4 * 16384 + 255) / 256, 256, 0, stream>>>(W2, W7, W3, W4, (ushort*)wpack, v3);
    // 3) hop 1: recompute-gather from (x, ea_sum) scalars -> aggB ; MFMA gemm -> embB
    k_gather1<<<(N_NODES * 64 + 255) / 256, 256, 0, stream>>>(pxe, offs, csr, W1, v3, aggB);
    k_gemm<false><<<(N_NODES + 63) / 64, 256, 0, stream>>>(
        aggB, w2p1, W1 + 1 * HID, v3 + 1 * HID, x, ea_sum, embB, nullptr, nullptr, nullptr);
    // 4) hop 2: gather embB -> aggB ; MFMA gemm + W7 head -> embA, out partial
    k_gather<<<(N_NODES * 64 + 255) / 256, 256, 0, stream>>>(embB, offs, csr, aggB);
    k_gemm<true><<<(N_NODES + 63) / 64, 256, 0, stream>>>(
        aggB, w2p2, W1 + 2 * HID, v3 + 2 * HID, x, ea_sum, embA, w7p, W5, out);
    // 5) graph pooling (parallel, branch-free)
    k_pool2<<<NGRAPH * 16, 256, 0, stream>>>(embA, gstart, pooled);
    // 6) per-graph scalars
    k_graph<<<NGRAPH, 128, 0, stream>>>(pooled, W6, W5, s_g);
    // 7) add graph term + bias
    k_addsg<<<(N_NODES + 255) / 256, 256, 0, stream>>>(out, bat, s_g, b5);
}

// Round 7
// 304.160 us; speedup vs baseline: 3.1488x; 1.0631x over previous
//
#include <hip/hip_runtime.h>
#include <hip/hip_bf16.h>

#define N_NODES 50000
#define N_EDGES 1600000
#define NGRAPH  16
#define HID     128

#define RPB   128                           // rows per bucket
#define NB    ((N_NODES + RPB - 1) / RPB)   // 391 buckets
#define NBLK  256                           // partition blocks
#define EPB   ((N_EDGES + NBLK - 1) / NBLK) // 6250 edges per partition block

typedef unsigned int uint32;
typedef unsigned short ushort;
typedef __attribute__((ext_vector_type(8))) short bf16x8;
typedef __attribute__((ext_vector_type(4))) float f32x4;
typedef __attribute__((ext_vector_type(2))) float f32x2;

// bf16 round-to-nearest-even helpers
__device__ __forceinline__ uint32 bf16r(float f) {
    uint32 b = __float_as_uint(f);
    return (b + 0x7fffu + ((b >> 16) & 1u)) >> 16;
}
__device__ __forceinline__ uint32 pack_bf16(float lo, float hi) {
    return bf16r(lo) | (bf16r(hi) << 16);
}
__device__ __forceinline__ float bf_lo(uint32 u) { return __uint_as_float(u << 16); }
__device__ __forceinline__ float bf_hi(uint32 u) { return __uint_as_float(u & 0xffff0000u); }

// ---------------- zero init ----------------
__global__ __launch_bounds__(256) void k_zero(float* p, int n) {
    int i = blockIdx.x * 256 + threadIdx.x;
    if (i < n) p[i] = 0.f;
}

// ---------------- graph boundaries: gstart[g] = lower_bound(batch, g) ----------------
__global__ __launch_bounds__(64) void k_bnd(const int* __restrict__ batch,
                                            int* __restrict__ gstart) {
    int g = threadIdx.x;
    if (g > NGRAPH) return;
    int lo = 0, hi = N_NODES;
    while (lo < hi) {
        int mid = (lo + hi) >> 1;
        if (batch[mid] < g) lo = mid + 1; else hi = mid;
    }
    gstart[g] = lo;
}

// ---------------- P1: per-(bucket,block) histogram ----------------
__global__ __launch_bounds__(1024) void k_p1_hist(const int* __restrict__ row,
                                                  int* __restrict__ blkhist) {
    __shared__ int hist[NB];
    int tid = threadIdx.x, blk = blockIdx.x;
    for (int i = tid; i < NB; i += 1024) hist[i] = 0;
    __syncthreads();
    int s = blk * EPB, e = s + EPB; if (e > N_EDGES) e = N_EDGES;
    for (int i = s + tid; i < e; i += 1024)
        atomicAdd(&hist[row[i] >> 7], 1);
    __syncthreads();
    for (int i = tid; i < NB; i += 1024)
        blkhist[i * NBLK + blk] = hist[i];
}

// ------- P2a: per-bucket exclusive scan over its NBLK per-block counts -------
__global__ __launch_bounds__(NBLK) void k_p2a(int* __restrict__ blkhist,
                                              int* __restrict__ btot) {
    __shared__ int sums[NBLK];
    int t = threadIdx.x, b = blockIdx.x;
    int v = blkhist[b * NBLK + t];
    sums[t] = v;
    __syncthreads();
    for (int d = 1; d < NBLK; d <<= 1) {
        int u = (t >= d) ? sums[t - d] : 0;
        __syncthreads();
        sums[t] += u;
        __syncthreads();
    }
    blkhist[b * NBLK + t] = sums[t] - v;     // local exclusive
    if (t == NBLK - 1) btot[b] = sums[t];    // bucket total
}

// ------- P2b: scan bucket totals -> bucket bases -------
__global__ __launch_bounds__(512) void k_p2b(const int* __restrict__ btot,
                                             int* __restrict__ bbase) {
    __shared__ int sums[512];
    int t = threadIdx.x;
    int s = (t < NB) ? btot[t] : 0;
    sums[t] = s;
    __syncthreads();
    for (int d = 1; d < 512; d <<= 1) {
        int v = (t >= d) ? sums[t - d] : 0;
        __syncthreads();
        sums[t] += v;
        __syncthreads();
    }
    if (t < NB) {
        bbase[t] = sums[t] - s;
        if (t == NB - 1) bbase[NB] = sums[t]; // == E
    }
}

// ------- P3: scatter int2{rowlocal:8|col:16, ea} into bucket runs (LDS cursors) -------
__global__ __launch_bounds__(1024) void k_p3_part(const int* __restrict__ row,
                                                  const int* __restrict__ col,
                                                  const float* __restrict__ ea,
                                                  const int* __restrict__ blkhist,
                                                  const int* __restrict__ bbase,
                                                  int2* __restrict__ pea) {
    __shared__ int cur[NB];
    int tid = threadIdx.x, blk = blockIdx.x;
    for (int i = tid; i < NB; i += 1024)
        cur[i] = bbase[i] + blkhist[i * NBLK + blk];
    __syncthreads();
    int s = blk * EPB, e = s + EPB; if (e > N_EDGES) e = N_EDGES;
    for (int i = s + tid; i < e; i += 1024) {
        int r = row[i], c = col[i];
        float a = ea[i];
        int slot = atomicAdd(&cur[r >> 7], 1);
        pea[slot] = make_int2(((r & (RPB - 1)) << 16) | c, __float_as_int(a));
    }
}

// ------- P4a: per-bucket counts + ea_sum + local scan -> offs, pxe -------
__global__ __launch_bounds__(512) void k_p4a(const int2* __restrict__ pea,
                                             const int* __restrict__ bbase,
                                             const float* __restrict__ x,
                                             int* __restrict__ offs,
                                             float* __restrict__ ea_sum,
                                             float2* __restrict__ pxe) {
    __shared__ int   cnt[RPB];
    __shared__ float eas[RPB];
    __shared__ int   scan_s[RPB];
    int tid = threadIdx.x, b = blockIdx.x;
    if (tid < RPB) { cnt[tid] = 0; eas[tid] = 0.f; }
    __syncthreads();
    int s = bbase[b], e = bbase[b + 1];
    for (int i = s + tid; i < e; i += 512) {
        int2 p = pea[i];
        int lr = ((uint32)p.x) >> 16;
        atomicAdd(&cnt[lr], 1);
        atomicAdd(&eas[lr], __int_as_float(p.y));
    }
    __syncthreads();
    if (tid < RPB) scan_s[tid] = cnt[tid];
    __syncthreads();
    for (int d = 1; d < RPB; d <<= 1) {
        int v = 0;
        if (tid < RPB && tid >= d) v = scan_s[tid - d];
        __syncthreads();
        if (tid < RPB) scan_s[tid] += v;
        __syncthreads();
    }
    int nbase = b * RPB;
    if (tid < RPB) {
        int excl = scan_s[tid] - cnt[tid];
        int n = nbase + tid;
        if (n < N_NODES) {
            offs[n] = s + excl;
            ea_sum[n] = eas[tid];
            pxe[n] = make_float2(x[n], eas[tid]);
        }
    }
    if (b == NB - 1 && tid == 0) offs[N_NODES] = e;
}

// ------- P4b: scatter csr + CSR-ordered payload pxec[slot] = pxe[col] -------
__global__ __launch_bounds__(512) void k_p4b(const int2* __restrict__ pea,
                                             const int* __restrict__ bbase,
                                             const int* __restrict__ offs,
                                             const float2* __restrict__ pxe,
                                             int* __restrict__ csr,
                                             float2* __restrict__ pxec) {
    __shared__ int cur[RPB];
    int tid = threadIdx.x, b = blockIdx.x;
    int nbase = b * RPB;
    if (tid < RPB) cur[tid] = (nbase + tid < N_NODES) ? offs[nbase + tid] : 0;
    __syncthreads();
    int s = bbase[b], e = bbase[b + 1];
    for (int i = s + tid; i < e; i += 512) {
        int2 p = pea[i];
        int c = p.x & 0xFFFF;
        int slot = atomicAdd(&cur[((uint32)p.x) >> 16], 1);
        csr[slot] = c;
        pxec[slot] = pxe[c];   // 400 KB table, L2-resident
    }
}

// ------- prep: pack W2 (x3) + W7 into MFMA B-fragment order (bf16); v3 = W3@relu(W4) -------
__global__ __launch_bounds__(256) void k_prep(const float* __restrict__ W2,
                                              const float* __restrict__ W7,
                                              const float* __restrict__ W3,
                                              const float* __restrict__ W4,
                                              ushort* __restrict__ wpack,  // 4 layers x 16384
                                              float* __restrict__ v3) {
    int idx = blockIdx.x * 256 + threadIdx.x;
    if (idx < 4 * 16384) {
        int m = idx >> 14, f = idx & 16383;
        int j = f & 7, lane = (f >> 3) & 63, kk = (f >> 9) & 3, t = (f >> 11) & 7;
        int hp = t * 16 + (lane & 15);
        int k  = kk * 32 + ((lane >> 4) & 3) * 8 + j;
        const float* src = (m < 3) ? (W2 + m * HID * HID) : W7;
        wpack[idx] = (ushort)bf16r(src[hp * HID + k]);
    }
    if (idx < 3 * HID) {
        int l = idx / HID, hp = idx % HID;
        float acc = 0.f;
        for (int h = 0; h < HID; h++)
            acc += W3[l * HID * HID + hp * HID + h] * fmaxf(W4[l * HID + h], 0.f);
        v3[idx] = acc;
    }
}

// ------- hop-1 gather by recompute, streaming CSR-ordered payload (no indirection) -------
// agg[n][h] = sum_c relu(x_c*w1[h] + es_c*v3[h]); lane owns h-pair; packed f32x2 math
__global__ __launch_bounds__(256) void k_gather1(const float2* __restrict__ pxec,
                                                 const int* __restrict__ offs,
                                                 const float* __restrict__ w1,
                                                 const float* __restrict__ v3,
                                                 uint32* __restrict__ agg) {
    int node = (blockIdx.x * 256 + threadIdx.x) >> 6;
    int lane = threadIdx.x & 63;
    if (node >= N_NODES) return;
    f32x2 w1v = {w1[2 * lane], w1[2 * lane + 1]};
    f32x2 v3v = {v3[2 * lane], v3[2 * lane + 1]};
    const f32x2 zero = {0.f, 0.f};
    int s = offs[node], e = offs[node + 1];
    f32x2 acc[4] = {zero, zero, zero, zero};
    int j = s;
    for (; j + 8 <= e; j += 8) {
        float2 p[8];
#pragma unroll
        for (int u = 0; u < 8; u++) p[u] = pxec[j + u];   // broadcast, contiguous
#pragma unroll
        for (int u = 0; u < 8; u++) {
            f32x2 px = {p[u].x, p[u].x};
            f32x2 pe = {p[u].y, p[u].y};
            f32x2 r = __builtin_elementwise_fma(px, w1v, pe * v3v);
            acc[u & 3] += __builtin_elementwise_max(r, zero);
        }
    }
    for (; j < e; j++) {
        float2 p = pxec[j];
        f32x2 px = {p.x, p.x};
        f32x2 pe = {p.y, p.y};
        f32x2 r = __builtin_elementwise_fma(px, w1v, pe * v3v);
        acc[0] += __builtin_elementwise_max(r, zero);
    }
    f32x2 rs = (acc[0] + acc[1]) + (acc[2] + acc[3]);
    agg[(size_t)node * 64 + lane] = pack_bf16(rs.x, rs.y);
}

// ------- hop-2 gather: coalesced csr chunk + shfl broadcast; 8 row-loads in flight -------
__global__ __launch_bounds__(256) void k_gather(const uint32* __restrict__ emb,
                                                const int* __restrict__ offs,
                                                const int* __restrict__ csr,
                                                uint32* __restrict__ agg) {
    int node = (blockIdx.x * 256 + threadIdx.x) >> 6;
    int lane = threadIdx.x & 63;
    if (node >= N_NODES) return;
    int s = offs[node], e = offs[node + 1];
    float ax[8] = {0.f}, ay[8] = {0.f};
    for (int base = s; base < e; base += 64) {
        int idx = base + lane;
        int cv = (idx < e) ? csr[idx] : 0;     // one coalesced load per 64 edges
        int cnt = e - base; if (cnt > 64) cnt = 64;
        int j = 0;
        for (; j + 8 <= cnt; j += 8) {
            uint32 v[8];
#pragma unroll
            for (int u = 0; u < 8; u++) {
                int c = __shfl(cv, j + u);
                v[u] = emb[(size_t)c * 64 + lane];
            }
#pragma unroll
            for (int u = 0; u < 8; u++) { ax[u] += bf_lo(v[u]); ay[u] += bf_hi(v[u]); }
        }
        for (; j < cnt; j++) {
            int c = __shfl(cv, j);
            uint32 u = emb[(size_t)c * 64 + lane];
            ax[0] += bf_lo(u); ay[0] += bf_hi(u);
        }
    }
    float rx = ((ax[0] + ax[1]) + (ax[2] + ax[3])) + ((ax[4] + ax[5]) + (ax[6] + ax[7]));
    float ry = ((ay[0] + ay[1]) + (ay[2] + ay[3])) + ((ay[4] + ay[5]) + (ay[6] + ay[7]));
    agg[(size_t)node * 64 + lane] = pack_bf16(rx, ry);
}

#define LROW 136  // padded LDS row, bf16 elems

// ------- MFMA GEMM hop: emb = relu(agg @ W2T + x*w1 + ea*v3); LAST fuses W7-head -------
template <bool LAST>
__global__ __launch_bounds__(256) void k_gemm(const uint32* __restrict__ agg,   // bf16 [N][64u32]
                                              const ushort* __restrict__ w2p,   // B-frag packed
                                              const float* __restrict__ w1l,
                                              const float* __restrict__ v3l,
                                              const float* __restrict__ x,
                                              const float* __restrict__ ea_sum,
                                              uint32* __restrict__ embOut,
                                              const ushort* __restrict__ w7p,
                                              const float* __restrict__ W5,
                                              float* __restrict__ outp) {
    __shared__ ushort tile[64 * LROW]; // 17408 B
    int tid = threadIdx.x;
    int tbase = blockIdx.x * 64;
    {
        const uint2* src = (const uint2*)(agg + (size_t)tbase * 64);
        int vn = N_NODES - tbase; if (vn > 64) vn = 64;
        int lim = vn * 32;
        for (int i = tid; i < 64 * 32; i += 256) {
            uint2 u = (i < lim) ? src[i] : make_uint2(0u, 0u);
            int r = i >> 5, c4 = (i & 31) * 4;
            *(uint2*)&tile[r * LROW + c4] = u;
        }
    }
    __syncthreads();
    int wv = tid >> 6, lane = tid & 63;
    int n0 = lane & 15, quad = lane >> 4;
    int arow = wv * 16 + n0;
    bf16x8 a0 = *(const bf16x8*)&tile[arow * LROW + 0 * 32 + quad * 8];
    bf16x8 a1 = *(const bf16x8*)&tile[arow * LROW + 1 * 32 + quad * 8];
    bf16x8 a2 = *(const bf16x8*)&tile[arow * LROW + 2 * 32 + quad * 8];
    bf16x8 a3 = *(const bf16x8*)&tile[arow * LROW + 3 * 32 + quad * 8];
    const bf16x8* wb = (const bf16x8*)w2p;
    f32x4 acc[8];
#pragma unroll
    for (int t = 0; t < 8; t++) {
        f32x4 c = {0.f, 0.f, 0.f, 0.f};
        c = __builtin_amdgcn_mfma_f32_16x16x32_bf16(a0, wb[(t * 4 + 0) * 64 + lane], c, 0, 0, 0);
        c = __builtin_amdgcn_mfma_f32_16x16x32_bf16(a1, wb[(t * 4 + 1) * 64 + lane], c, 0, 0, 0);
        c = __builtin_amdgcn_mfma_f32_16x16x32_bf16(a2, wb[(t * 4 + 2) * 64 + lane], c, 0, 0, 0);
        c = __builtin_amdgcn_mfma_f32_16x16x32_bf16(a3, wb[(t * 4 + 3) * 64 + lane], c, 0, 0, 0);
        acc[t] = c;
    }
    float xs[4], es[4];
#pragma unroll
    for (int r = 0; r < 4; r++) {
        int n = tbase + wv * 16 + quad * 4 + r;
        xs[r] = (n < N_NODES) ? x[n] : 0.f;
        es[r] = (n < N_NODES) ? ea_sum[n] : 0.f;
    }
#pragma unroll
    for (int t = 0; t < 8; t++) {
        int hp = t * 16 + n0;
        float w1v = w1l[hp], v3v = v3l[hp];
#pragma unroll
        for (int r = 0; r < 4; r++) {
            float v = fmaxf(acc[t][r] + xs[r] * w1v + es[r] * v3v, 0.f);
            tile[(wv * 16 + quad * 4 + r) * LROW + hp] = (ushort)bf16r(v);
        }
    }
    __syncthreads();
    {
        int vn = N_NODES - tbase; if (vn > 64) vn = 64;
        for (int i = tid; i < 64 * 32; i += 256) {
            int r = i >> 5, c4 = (i & 31) * 4;
            if (r < vn) {
                uint2 u = *(const uint2*)&tile[r * LROW + c4];
                *(uint2*)(embOut + (size_t)(tbase + r) * 64 + (size_t)(i & 31) * 2) = u;
            }
        }
    }
    if (LAST) {
        bf16x8 b0 = *(const bf16x8*)&tile[arow * LROW + 0 * 32 + quad * 8];
        bf16x8 b1 = *(const bf16x8*)&tile[arow * LROW + 1 * 32 + quad * 8];
        bf16x8 b2 = *(const bf16x8*)&tile[arow * LROW + 2 * 32 + quad * 8];
        bf16x8 b3 = *(const bf16x8*)&tile[arow * LROW + 3 * 32 + quad * 8];
        const bf16x8* w7 = (const bf16x8*)w7p;
        float p[4] = {0.f, 0.f, 0.f, 0.f};
#pragma unroll
        for (int t = 0; t < 8; t++) {
            f32x4 c = {0.f, 0.f, 0.f, 0.f};
            c = __builtin_amdgcn_mfma_f32_16x16x32_bf16(b0, w7[(t * 4 + 0) * 64 + lane], c, 0, 0, 0);
            c = __builtin_amdgcn_mfma_f32_16x16x32_bf16(b1, w7[(t * 4 + 1) * 64 + lane], c, 0, 0, 0);
            c = __builtin_amdgcn_mfma_f32_16x16x32_bf16(b2, w7[(t * 4 + 2) * 64 + lane], c, 0, 0, 0);
            c = __builtin_amdgcn_mfma_f32_16x16x32_bf16(b3, w7[(t * 4 + 3) * 64 + lane], c, 0, 0, 0);
            float w5v = W5[128 + t * 16 + n0];
#pragma unroll
            for (int r = 0; r < 4; r++) p[r] += fmaxf(c[r], 0.f) * w5v;
        }
#pragma unroll
        for (int r = 0; r < 4; r++) {
            float v = p[r];
            v += __shfl_xor(v, 1);
            v += __shfl_xor(v, 2);
            v += __shfl_xor(v, 4);
            v += __shfl_xor(v, 8);
            int n = tbase + wv * 16 + quad * 4 + r;
            if (n0 == 0 && n < N_NODES) outp[n] = v;
        }
    }
}

// ------- pooling: 16 graphs x 16 chunks, branch-free, 4-node ILP -------
__global__ __launch_bounds__(256) void k_pool2(const uint32* __restrict__ emb,
                                               const int* __restrict__ gstart,
                                               float* __restrict__ pooled) {
    __shared__ float2 red[4][64];
    int bid = blockIdx.x;
    int g = bid >> 4, chunk = bid & 15;
    int gs = gstart[g], ge = gstart[g + 1];
    int len = ge - gs;
    int cs = gs + (int)(((long long)len * chunk) >> 4);
    int ce = gs + (int)(((long long)len * (chunk + 1)) >> 4);
    int sub = threadIdx.x >> 6, lane = threadIdx.x & 63;
    float ax = 0.f, ay = 0.f;
    for (int n = cs + sub; n < ce; n += 4) {
        uint32 u = emb[(size_t)n * 64 + lane];
        ax += bf_lo(u); ay += bf_hi(u);
    }
    red[sub][lane] = make_float2(ax, ay);
    __syncthreads();
    if (sub == 0) {
        float2 r0 = red[0][lane], r1 = red[1][lane], r2 = red[2][lane], r3 = red[3][lane];
        atomicAdd(&pooled[g * HID + 2 * lane],     (r0.x + r1.x) + (r2.x + r3.x));
        atomicAdd(&pooled[g * HID + 2 * lane + 1], (r0.y + r1.y) + (r2.y + r3.y));
    }
}

// ---------------- per-graph scalar: s_g = relu(pooled@W6T) . W5[:128] ----------------
__global__ __launch_bounds__(128) void k_graph(const float* __restrict__ pooled,
                                               const float* __restrict__ W6,
                                               const float* __restrict__ W5,
                                               float* __restrict__ s_g) {
    int g = blockIdx.x, hp = threadIdx.x;
    float acc = 0.f;
    for (int h = 0; h < HID; h++) acc += pooled[g * HID + h] * W6[hp * HID + h];
    float v = fmaxf(acc, 0.f) * W5[hp];
    __shared__ float red[HID];
    red[hp] = v;
    __syncthreads();
    for (int d = 64; d > 0; d >>= 1) {
        if (hp < d) red[hp] += red[hp + d];
        __syncthreads();
    }
    if (hp == 0) s_g[g] = red[0];
}

// ---------------- final add: out[n] += s_g[batch[n]] + b5 ----------------
__global__ __launch_bounds__(256) void k_addsg(float* __restrict__ out,
                                               const int* __restrict__ batch,
                                               const float* __restrict__ s_g,
                                               const float* __restrict__ b5) {
    int n = blockIdx.x * 256 + threadIdx.x;
    if (n < N_NODES) out[n] += s_g[batch[n]] + b5[0];
}

extern "C" void kernel_launch(void* const* d_in, const int* in_sizes, int n_in,
                              void* d_out, int out_size, void* d_ws, size_t ws_size,
                              hipStream_t stream) {
    (void)in_sizes; (void)n_in; (void)out_size; (void)ws_size;
    const float* x    = (const float*)d_in[0];
    const int*   ei   = (const int*)d_in[1];   // [2,E] flat: row then col
    const float* ea   = (const float*)d_in[2];
    const int*   bat  = (const int*)d_in[3];
    const float* W1   = (const float*)d_in[4]; // [3,128,1]
    const float* W2   = (const float*)d_in[5]; // [3,128,128]
    const float* W3   = (const float*)d_in[6];
    const float* W4   = (const float*)d_in[7]; // [3,128,1]
    const float* W5   = (const float*)d_in[8]; // [1,256]
    const float* b5   = (const float*)d_in[9];
    const float* W6   = (const float*)d_in[10];
    const float* W7   = (const float*)d_in[11];
    float* out = (float*)d_out;

    const int* row = ei;
    const int* col = ei + N_EDGES;

    // workspace layout (4B elems)
    float* wsf = (float*)d_ws;
    int*   wsi = (int*)d_ws;
    size_t o = 0;
    float* pooled = wsf + o; o += NGRAPH * HID;     // zeroed (atomic targets)
    float* s_g    = wsf + o; o += NGRAPH;           // zeroed
    size_t ztot = o;
    int*   offs   = wsi + o; o += N_NODES + 1;
    float* ea_sum = wsf + o; o += N_NODES;
    int*   gstart = wsi + o; o += NGRAPH + 1;
    int*   btot   = wsi + o; o += NB;
    int*   bbase  = wsi + o; o += NB + 1;
    float* v3     = wsf + o; o += 3 * HID;
    int*   blkh   = wsi + o; o += NB * NBLK;
    o = (o + 1) & ~(size_t)1;
    float2* pxe   = (float2*)(wsi + o); o += 2 * (size_t)N_NODES;
    o = (o + 3) & ~(size_t)3;
    ushort* wpack = (ushort*)(wsi + o); o += 4 * 16384 / 2;
    int*    csr   = wsi + o; o += N_EDGES;
    o = (o + 1) & ~(size_t)1;
    int2*   pea   = (int2*)(wsi + o); o += 2 * (size_t)N_EDGES;
    float2* pxec  = (float2*)(wsi + o); o += 2 * (size_t)N_EDGES;
    o = (o + 1) & ~(size_t)1;
    uint32* embA  = (uint32*)(wsi + o); o += (size_t)N_NODES * 64; // bf16 [N][128]
    uint32* embB  = (uint32*)(wsi + o); o += (size_t)N_NODES * 64;
    uint32* aggB  = (uint32*)(wsi + o); o += (size_t)N_NODES * 64;

    const ushort* w2p1 = wpack + 1 * 16384;
    const ushort* w2p2 = wpack + 2 * 16384;
    const ushort* w7p  = wpack + 3 * 16384;

    // 0) zero atomic accumulators + graph boundaries
    k_zero<<<(int)((ztot + 255) / 256), 256, 0, stream>>>((float*)d_ws, (int)ztot);
    k_bnd<<<1, 64, 0, stream>>>(bat, gstart);
    // 1) atomic-free CSR build + CSR-ordered hop-1 payload
    k_p1_hist<<<NBLK, 1024, 0, stream>>>(row, blkh);
    k_p2a<<<NB, NBLK, 0, stream>>>(blkh, btot);
    k_p2b<<<1, 512, 0, stream>>>(btot, bbase);
    k_p3_part<<<NBLK, 1024, 0, stream>>>(row, col, ea, blkh, bbase, pea);
    k_p4a<<<NB, 512, 0, stream>>>(pea, bbase, x, offs, ea_sum, pxe);
    k_p4b<<<NB, 512, 0, stream>>>(pea, bbase, offs, pxe, csr, pxec);
    // 2) weight prep: MFMA B-frag packs + v3
    k_prep<<<(4 * 16384 + 255) / 256, 256, 0, stream>>>(W2, W7, W3, W4, (ushort*)wpack, v3);
    // 3) hop 1: streaming recompute-gather -> aggB ; MFMA gemm -> embB
    k_gather1<<<(N_NODES * 64 + 255) / 256, 256, 0, stream>>>(pxec, offs, W1, v3, aggB);
    k_gemm<false><<<(N_NODES + 63) / 64, 256, 0, stream>>>(
        aggB, w2p1, W1 + 1 * HID, v3 + 1 * HID, x, ea_sum, embB, nullptr, nullptr, nullptr);
    // 4) hop 2: gather embB -> aggB ; MFMA gemm + W7 head -> embA, out partial
    k_gather<<<(N_NODES * 64 + 255) / 256, 256, 0, stream>>>(embB, offs, csr, aggB);
    k_gemm<true><<<(N_NODES + 63) / 64, 256, 0, stream>>>(
        aggB, w2p2, W1 + 2 * HID, v3 + 2 * HID, x, ea_sum, embA, w7p, W5, out);
    // 5) graph pooling (parallel, branch-free)
    k_pool2<<<NGRAPH * 16, 256, 0, stream>>>(embA, gstart, pooled);
    // 6) per-graph scalars
    k_graph<<<NGRAPH, 128, 0, stream>>>(pooled, W6, W5, s_g);
    // 7) add graph term + bias
    k_addsg<<<(N_NODES + 255) / 256, 256, 0, stream>>>(out, bat, s_g, b5);
}

// Round 8
// 283.748 us; speedup vs baseline: 3.3753x; 1.0719x over previous
//
#include <hip/hip_runtime.h>
#include <hip/hip_bf16.h>

#define N_NODES 50000
#define N_EDGES 1600000
#define NGRAPH  16
#define HID     128

#define RPB   128                           // rows per bucket
#define NB    ((N_NODES + RPB - 1) / RPB)   // 391 buckets
#define NBLK  256                           // partition blocks
#define EPB   ((N_EDGES + NBLK - 1) / NBLK) // 6250 edges per partition block

typedef unsigned int uint32;
typedef unsigned short ushort;
typedef unsigned char uchar;
typedef __attribute__((ext_vector_type(8))) short bf16x8;
typedef __attribute__((ext_vector_type(4))) float f32x4;
typedef __attribute__((ext_vector_type(2))) float f32x2;

// bf16 round-to-nearest-even helpers
__device__ __forceinline__ uint32 bf16r(float f) {
    uint32 b = __float_as_uint(f);
    return (b + 0x7fffu + ((b >> 16) & 1u)) >> 16;
}
__device__ __forceinline__ uint32 pack_bf16(float lo, float hi) {
    return bf16r(lo) | (bf16r(hi) << 16);
}
__device__ __forceinline__ float bf_lo(uint32 u) { return __uint_as_float(u << 16); }
__device__ __forceinline__ float bf_hi(uint32 u) { return __uint_as_float(u & 0xffff0000u); }

// ---------------- init: zero accumulators + graph boundaries ----------------
__global__ __launch_bounds__(256) void k_init(float* p, int n,
                                              const int* __restrict__ batch,
                                              int* __restrict__ gstart) {
    int i = blockIdx.x * 256 + threadIdx.x;
    if (i < n) p[i] = 0.f;
    if (i <= NGRAPH) {
        int lo = 0, hi = N_NODES;
        while (lo < hi) {
            int mid = (lo + hi) >> 1;
            if (batch[mid] < i) lo = mid + 1; else hi = mid;
        }
        gstart[i] = lo;
    }
}

// ---------------- P1: per-(bucket,block) histogram ----------------
__global__ __launch_bounds__(1024) void k_p1_hist(const int* __restrict__ row,
                                                  int* __restrict__ blkhist) {
    __shared__ int hist[NB];
    int tid = threadIdx.x, blk = blockIdx.x;
    for (int i = tid; i < NB; i += 1024) hist[i] = 0;
    __syncthreads();
    int s = blk * EPB, e = s + EPB; if (e > N_EDGES) e = N_EDGES;
    for (int i = s + tid; i < e; i += 1024)
        atomicAdd(&hist[row[i] >> 7], 1);
    __syncthreads();
    for (int i = tid; i < NB; i += 1024)
        blkhist[i * NBLK + blk] = hist[i];
}

// ------- P2a: per-bucket exclusive scan over its NBLK per-block counts -------
__global__ __launch_bounds__(NBLK) void k_p2a(int* __restrict__ blkhist,
                                              int* __restrict__ btot) {
    __shared__ int sums[NBLK];
    int t = threadIdx.x, b = blockIdx.x;
    int v = blkhist[b * NBLK + t];
    sums[t] = v;
    __syncthreads();
    for (int d = 1; d < NBLK; d <<= 1) {
        int u = (t >= d) ? sums[t - d] : 0;
        __syncthreads();
        sums[t] += u;
        __syncthreads();
    }
    blkhist[b * NBLK + t] = sums[t] - v;     // local exclusive
    if (t == NBLK - 1) btot[b] = sums[t];    // bucket total
}

// ------- P2b: scan bucket totals -> bucket bases -------
__global__ __launch_bounds__(512) void k_p2b(const int* __restrict__ btot,
                                             int* __restrict__ bbase) {
    __shared__ int sums[512];
    int t = threadIdx.x;
    int s = (t < NB) ? btot[t] : 0;
    sums[t] = s;
    __syncthreads();
    for (int d = 1; d < 512; d <<= 1) {
        int v = (t >= d) ? sums[t - d] : 0;
        __syncthreads();
        sums[t] += v;
        __syncthreads();
    }
    if (t < NB) {
        bbase[t] = sums[t] - s;
        if (t == NB - 1) bbase[NB] = sums[t]; // == E
    }
}

// ------- P3: scatter int2{rowlocal:8|col:16, ea} into bucket runs (LDS cursors) -------
__global__ __launch_bounds__(1024) void k_p3_part(const int* __restrict__ row,
                                                  const int* __restrict__ col,
                                                  const float* __restrict__ ea,
                                                  const int* __restrict__ blkhist,
                                                  const int* __restrict__ bbase,
                                                  int2* __restrict__ pea) {
    __shared__ int cur[NB];
    int tid = threadIdx.x, blk = blockIdx.x;
    for (int i = tid; i < NB; i += 1024)
        cur[i] = bbase[i] + blkhist[i * NBLK + blk];
    __syncthreads();
    int s = blk * EPB, e = s + EPB; if (e > N_EDGES) e = N_EDGES;
    for (int i = s + tid; i < e; i += 1024) {
        int r = row[i], c = col[i];
        float a = ea[i];
        int slot = atomicAdd(&cur[r >> 7], 1);
        pea[slot] = make_int2(((r & (RPB - 1)) << 16) | c, __float_as_int(a));
    }
}

// ------- P4a: per-bucket counts + ea_sum + local scan -> offs, pxe -------
__global__ __launch_bounds__(512) void k_p4a(const int2* __restrict__ pea,
                                             const int* __restrict__ bbase,
                                             const float* __restrict__ x,
                                             int* __restrict__ offs,
                                             float* __restrict__ ea_sum,
                                             float2* __restrict__ pxe) {
    __shared__ int   cnt[RPB];
    __shared__ float eas[RPB];
    __shared__ int   scan_s[RPB];
    int tid = threadIdx.x, b = blockIdx.x;
    if (tid < RPB) { cnt[tid] = 0; eas[tid] = 0.f; }
    __syncthreads();
    int s = bbase[b], e = bbase[b + 1];
    for (int i = s + tid; i < e; i += 512) {
        int2 p = pea[i];
        int lr = ((uint32)p.x) >> 16;
        atomicAdd(&cnt[lr], 1);
        atomicAdd(&eas[lr], __int_as_float(p.y));
    }
    __syncthreads();
    if (tid < RPB) scan_s[tid] = cnt[tid];
    __syncthreads();
    for (int d = 1; d < RPB; d <<= 1) {
        int v = 0;
        if (tid < RPB && tid >= d) v = scan_s[tid - d];
        __syncthreads();
        if (tid < RPB) scan_s[tid] += v;
        __syncthreads();
    }
    int nbase = b * RPB;
    if (tid < RPB) {
        int excl = scan_s[tid] - cnt[tid];
        int n = nbase + tid;
        if (n < N_NODES) {
            offs[n] = s + excl;
            ea_sum[n] = eas[tid];
            pxe[n] = make_float2(x[n], eas[tid]);
        }
    }
    if (b == NB - 1 && tid == 0) offs[N_NODES] = e;
}

// ------- P4b: scatter csr + CSR-ordered payload pxec[slot] = pxe[col] -------
__global__ __launch_bounds__(512) void k_p4b(const int2* __restrict__ pea,
                                             const int* __restrict__ bbase,
                                             const int* __restrict__ offs,
                                             const float2* __restrict__ pxe,
                                             int* __restrict__ csr,
                                             float2* __restrict__ pxec) {
    __shared__ int cur[RPB];
    int tid = threadIdx.x, b = blockIdx.x;
    int nbase = b * RPB;
    if (tid < RPB) cur[tid] = (nbase + tid < N_NODES) ? offs[nbase + tid] : 0;
    __syncthreads();
    int s = bbase[b], e = bbase[b + 1];
    for (int i = s + tid; i < e; i += 512) {
        int2 p = pea[i];
        int c = p.x & 0xFFFF;
        int slot = atomicAdd(&cur[((uint32)p.x) >> 16], 1);
        csr[slot] = c;
        pxec[slot] = pxe[c];   // 400 KB table, L2-resident
    }
}

// ------- prep: pack W2 (x3) + W7 into MFMA B-fragment order (bf16); v3 = W3@relu(W4) -------
__global__ __launch_bounds__(256) void k_prep(const float* __restrict__ W2,
                                              const float* __restrict__ W7,
                                              const float* __restrict__ W3,
                                              const float* __restrict__ W4,
                                              ushort* __restrict__ wpack,  // 4 layers x 16384
                                              float* __restrict__ v3) {
    int idx = blockIdx.x * 256 + threadIdx.x;
    if (idx < 4 * 16384) {
        int m = idx >> 14, f = idx & 16383;
        int j = f & 7, lane = (f >> 3) & 63, kk = (f >> 9) & 3, t = (f >> 11) & 7;
        int hp = t * 16 + (lane & 15);
        int k  = kk * 32 + ((lane >> 4) & 3) * 8 + j;
        const float* src = (m < 3) ? (W2 + m * HID * HID) : W7;
        wpack[idx] = (ushort)bf16r(src[hp * HID + k]);
    }
    if (idx < 3 * HID) {
        int l = idx / HID, hp = idx % HID;
        float acc = 0.f;
        for (int h = 0; h < HID; h++)
            acc += W3[l * HID * HID + hp * HID + h] * fmaxf(W4[l * HID + h], 0.f);
        v3[idx] = acc;
    }
}

// ------- hop-1 gather by recompute, streaming CSR-ordered payload (no indirection) -------
__global__ __launch_bounds__(256) void k_gather1(const float2* __restrict__ pxec,
                                                 const int* __restrict__ offs,
                                                 const float* __restrict__ w1,
                                                 const float* __restrict__ v3,
                                                 uint32* __restrict__ agg) {
    int node = (blockIdx.x * 256 + threadIdx.x) >> 6;
    int lane = threadIdx.x & 63;
    if (node >= N_NODES) return;
    f32x2 w1v = {w1[2 * lane], w1[2 * lane + 1]};
    f32x2 v3v = {v3[2 * lane], v3[2 * lane + 1]};
    const f32x2 zero = {0.f, 0.f};
    int s = offs[node], e = offs[node + 1];
    f32x2 acc[4] = {zero, zero, zero, zero};
    int j = s;
    for (; j + 8 <= e; j += 8) {
        float2 p[8];
#pragma unroll
        for (int u = 0; u < 8; u++) p[u] = pxec[j + u];   // broadcast, contiguous
#pragma unroll
        for (int u = 0; u < 8; u++) {
            f32x2 px = {p[u].x, p[u].x};
            f32x2 pe = {p[u].y, p[u].y};
            f32x2 r = __builtin_elementwise_fma(px, w1v, pe * v3v);
            acc[u & 3] += __builtin_elementwise_max(r, zero);
        }
    }
    for (; j < e; j++) {
        float2 p = pxec[j];
        f32x2 px = {p.x, p.x};
        f32x2 pe = {p.y, p.y};
        f32x2 r = __builtin_elementwise_fma(px, w1v, pe * v3v);
        acc[0] += __builtin_elementwise_max(r, zero);
    }
    f32x2 rs = (acc[0] + acc[1]) + (acc[2] + acc[3]);
    agg[(size_t)node * 64 + lane] = pack_bf16(rs.x, rs.y);
}

// ------- hop-2 gather over fp8 emb rows (128 B): coalesced csr + shfl; x64 rescale -------
__global__ __launch_bounds__(256) void k_gather(const uchar* __restrict__ emb8,
                                                const int* __restrict__ offs,
                                                const int* __restrict__ csr,
                                                uint32* __restrict__ agg) {
    int node = (blockIdx.x * 256 + threadIdx.x) >> 6;
    int lane = threadIdx.x & 63;
    if (node >= N_NODES) return;
    int s = offs[node], e = offs[node + 1];
    float ax[8] = {0.f}, ay[8] = {0.f};
    for (int base = s; base < e; base += 64) {
        int idx = base + lane;
        int cv = (idx < e) ? csr[idx] : 0;     // one coalesced load per 64 edges
        int cnt = e - base; if (cnt > 64) cnt = 64;
        int j = 0;
        for (; j + 8 <= cnt; j += 8) {
            int h16[8];
#pragma unroll
            for (int u = 0; u < 8; u++) {
                int c = __shfl(cv, j + u);
                h16[u] = *(const ushort*)(emb8 + (size_t)c * 128 + 2 * lane);
            }
#pragma unroll
            for (int u = 0; u < 8; u++) {
                f32x2 d = __builtin_amdgcn_cvt_pk_f32_fp8(h16[u], false);
                ax[u] += d.x; ay[u] += d.y;
            }
        }
        for (; j < cnt; j++) {
            int c = __shfl(cv, j);
            int h = *(const ushort*)(emb8 + (size_t)c * 128 + 2 * lane);
            f32x2 d = __builtin_amdgcn_cvt_pk_f32_fp8(h, false);
            ax[0] += d.x; ay[0] += d.y;
        }
    }
    float rx = (((ax[0] + ax[1]) + (ax[2] + ax[3])) + ((ax[4] + ax[5]) + (ax[6] + ax[7]))) * 64.f;
    float ry = (((ay[0] + ay[1]) + (ay[2] + ay[3])) + ((ay[4] + ay[5]) + (ay[6] + ay[7]))) * 64.f;
    agg[(size_t)node * 64 + lane] = pack_bf16(rx, ry);
}

#define LROW 136  // padded LDS row, bf16 elems

// ------- MFMA GEMM hop: emb = relu(agg @ W2T + x*w1 + ea*v3) -------
// !LAST: emit fp8 emb (scale 2^-6, row 128 B).  LAST: emit bf16 emb + fused W7-head.
template <bool LAST>
__global__ __launch_bounds__(256) void k_gemm(const uint32* __restrict__ agg,   // bf16 [N][64u32]
                                              const ushort* __restrict__ w2p,   // B-frag packed
                                              const float* __restrict__ w1l,
                                              const float* __restrict__ v3l,
                                              const float* __restrict__ x,
                                              const float* __restrict__ ea_sum,
                                              uint32* __restrict__ embOut,      // bf16 (LAST)
                                              uchar* __restrict__ emb8Out,      // fp8 (!LAST)
                                              const ushort* __restrict__ w7p,
                                              const float* __restrict__ W5,
                                              float* __restrict__ outp) {
    __shared__ ushort tile[64 * LROW]; // 17408 B
    int tid = threadIdx.x;
    int tbase = blockIdx.x * 64;
    {
        const uint2* src = (const uint2*)(agg + (size_t)tbase * 64);
        int vn = N_NODES - tbase; if (vn > 64) vn = 64;
        int lim = vn * 32;
        for (int i = tid; i < 64 * 32; i += 256) {
            uint2 u = (i < lim) ? src[i] : make_uint2(0u, 0u);
            int r = i >> 5, c4 = (i & 31) * 4;
            *(uint2*)&tile[r * LROW + c4] = u;
        }
    }
    __syncthreads();
    int wv = tid >> 6, lane = tid & 63;
    int n0 = lane & 15, quad = lane >> 4;
    int arow = wv * 16 + n0;
    bf16x8 a0 = *(const bf16x8*)&tile[arow * LROW + 0 * 32 + quad * 8];
    bf16x8 a1 = *(const bf16x8*)&tile[arow * LROW + 1 * 32 + quad * 8];
    bf16x8 a2 = *(const bf16x8*)&tile[arow * LROW + 2 * 32 + quad * 8];
    bf16x8 a3 = *(const bf16x8*)&tile[arow * LROW + 3 * 32 + quad * 8];
    const bf16x8* wb = (const bf16x8*)w2p;
    f32x4 acc[8];
#pragma unroll
    for (int t = 0; t < 8; t++) {
        f32x4 c = {0.f, 0.f, 0.f, 0.f};
        c = __builtin_amdgcn_mfma_f32_16x16x32_bf16(a0, wb[(t * 4 + 0) * 64 + lane], c, 0, 0, 0);
        c = __builtin_amdgcn_mfma_f32_16x16x32_bf16(a1, wb[(t * 4 + 1) * 64 + lane], c, 0, 0, 0);
        c = __builtin_amdgcn_mfma_f32_16x16x32_bf16(a2, wb[(t * 4 + 2) * 64 + lane], c, 0, 0, 0);
        c = __builtin_amdgcn_mfma_f32_16x16x32_bf16(a3, wb[(t * 4 + 3) * 64 + lane], c, 0, 0, 0);
        acc[t] = c;
    }
    float xs[4], es[4];
#pragma unroll
    for (int r = 0; r < 4; r++) {
        int n = tbase + wv * 16 + quad * 4 + r;
        xs[r] = (n < N_NODES) ? x[n] : 0.f;
        es[r] = (n < N_NODES) ? ea_sum[n] : 0.f;
    }
    if (!LAST) {
        // epilogue: fp8 output, scale 2^-6 (exact pow2; rescaled x64 in k_gather)
        uchar* stile = (uchar*)tile;   // rows stride 136 B; wave-private rows
#pragma unroll
        for (int t = 0; t < 8; t++) {
            int hp = t * 16 + n0;
            float w1v = w1l[hp], v3v = v3l[hp];
#pragma unroll
            for (int r = 0; r < 4; r++) {
                float v = fmaxf(acc[t][r] + xs[r] * w1v + es[r] * v3v, 0.f) * 0.015625f;
                int enc = __builtin_amdgcn_cvt_pk_fp8_f32(v, v, 0, false);
                stile[(wv * 16 + quad * 4 + r) * 136 + hp] = (uchar)(enc & 0xff);
            }
        }
        __syncthreads();
        int vn = N_NODES - tbase; if (vn > 64) vn = 64;
        for (int i = tid; i < 64 * 32; i += 256) {
            int r = i >> 5, c4 = (i & 31) * 4;
            if (r < vn) {
                uint32 u = *(const uint32*)&stile[r * 136 + c4];
                *(uint32*)(emb8Out + (size_t)(tbase + r) * 128 + c4) = u;
            }
        }
    } else {
        // epilogue: bf16 output back through LDS + fused W7 head
#pragma unroll
        for (int t = 0; t < 8; t++) {
            int hp = t * 16 + n0;
            float w1v = w1l[hp], v3v = v3l[hp];
#pragma unroll
            for (int r = 0; r < 4; r++) {
                float v = fmaxf(acc[t][r] + xs[r] * w1v + es[r] * v3v, 0.f);
                tile[(wv * 16 + quad * 4 + r) * LROW + hp] = (ushort)bf16r(v);
            }
        }
        __syncthreads();
        {
            int vn = N_NODES - tbase; if (vn > 64) vn = 64;
            for (int i = tid; i < 64 * 32; i += 256) {
                int r = i >> 5, c4 = (i & 31) * 4;
                if (r < vn) {
                    uint2 u = *(const uint2*)&tile[r * LROW + c4];
                    *(uint2*)(embOut + (size_t)(tbase + r) * 64 + (size_t)(i & 31) * 2) = u;
                }
            }
        }
        bf16x8 b0 = *(const bf16x8*)&tile[arow * LROW + 0 * 32 + quad * 8];
        bf16x8 b1 = *(const bf16x8*)&tile[arow * LROW + 1 * 32 + quad * 8];
        bf16x8 b2 = *(const bf16x8*)&tile[arow * LROW + 2 * 32 + quad * 8];
        bf16x8 b3 = *(const bf16x8*)&tile[arow * LROW + 3 * 32 + quad * 8];
        const bf16x8* w7 = (const bf16x8*)w7p;
        float p[4] = {0.f, 0.f, 0.f, 0.f};
#pragma unroll
        for (int t = 0; t < 8; t++) {
            f32x4 c = {0.f, 0.f, 0.f, 0.f};
            c = __builtin_amdgcn_mfma_f32_16x16x32_bf16(b0, w7[(t * 4 + 0) * 64 + lane], c, 0, 0, 0);
            c = __builtin_amdgcn_mfma_f32_16x16x32_bf16(b1, w7[(t * 4 + 1) * 64 + lane], c, 0, 0, 0);
            c = __builtin_amdgcn_mfma_f32_16x16x32_bf16(b2, w7[(t * 4 + 2) * 64 + lane], c, 0, 0, 0);
            c = __builtin_amdgcn_mfma_f32_16x16x32_bf16(b3, w7[(t * 4 + 3) * 64 + lane], c, 0, 0, 0);
            float w5v = W5[128 + t * 16 + n0];
#pragma unroll
            for (int r = 0; r < 4; r++) p[r] += fmaxf(c[r], 0.f) * w5v;
        }
#pragma unroll
        for (int r = 0; r < 4; r++) {
            float v = p[r];
            v += __shfl_xor(v, 1);
            v += __shfl_xor(v, 2);
            v += __shfl_xor(v, 4);
            v += __shfl_xor(v, 8);
            int n = tbase + wv * 16 + quad * 4 + r;
            if (n0 == 0 && n < N_NODES) outp[n] = v;
        }
    }
}

// ------- pooling: 16 graphs x 16 chunks, branch-free, 4-node ILP -------
__global__ __launch_bounds__(256) void k_pool2(const uint32* __restrict__ emb,
                                               const int* __restrict__ gstart,
                                               float* __restrict__ pooled) {
    __shared__ float2 red[4][64];
    int bid = blockIdx.x;
    int g = bid >> 4, chunk = bid & 15;
    int gs = gstart[g], ge = gstart[g + 1];
    int len = ge - gs;
    int cs = gs + (int)(((long long)len * chunk) >> 4);
    int ce = gs + (int)(((long long)len * (chunk + 1)) >> 4);
    int sub = threadIdx.x >> 6, lane = threadIdx.x & 63;
    float ax = 0.f, ay = 0.f;
    for (int n = cs + sub; n < ce; n += 4) {
        uint32 u = emb[(size_t)n * 64 + lane];
        ax += bf_lo(u); ay += bf_hi(u);
    }
    red[sub][lane] = make_float2(ax, ay);
    __syncthreads();
    if (sub == 0) {
        float2 r0 = red[0][lane], r1 = red[1][lane], r2 = red[2][lane], r3 = red[3][lane];
        atomicAdd(&pooled[g * HID + 2 * lane],     (r0.x + r1.x) + (r2.x + r3.x));
        atomicAdd(&pooled[g * HID + 2 * lane + 1], (r0.y + r1.y) + (r2.y + r3.y));
    }
}

// ---------------- per-graph scalar: s_g = relu(pooled@W6T) . W5[:128] ----------------
__global__ __launch_bounds__(128) void k_graph(const float* __restrict__ pooled,
                                               const float* __restrict__ W6,
                                               const float* __restrict__ W5,
                                               float* __restrict__ s_g) {
    int g = blockIdx.x, hp = threadIdx.x;
    float acc = 0.f;
    for (int h = 0; h < HID; h++) acc += pooled[g * HID + h] * W6[hp * HID + h];
    float v = fmaxf(acc, 0.f) * W5[hp];
    __shared__ float red[HID];
    red[hp] = v;
    __syncthreads();
    for (int d = 64; d > 0; d >>= 1) {
        if (hp < d) red[hp] += red[hp + d];
        __syncthreads();
    }
    if (hp == 0) s_g[g] = red[0];
}

// ---------------- final add: out[n] += s_g[batch[n]] + b5 ----------------
__global__ __launch_bounds__(256) void k_addsg(float* __restrict__ out,
                                               const int* __restrict__ batch,
                                               const float* __restrict__ s_g,
                                               const float* __restrict__ b5) {
    int n = blockIdx.x * 256 + threadIdx.x;
    if (n < N_NODES) out[n] += s_g[batch[n]] + b5[0];
}

extern "C" void kernel_launch(void* const* d_in, const int* in_sizes, int n_in,
                              void* d_out, int out_size, void* d_ws, size_t ws_size,
                              hipStream_t stream) {
    (void)in_sizes; (void)n_in; (void)out_size; (void)ws_size;
    const float* x    = (const float*)d_in[0];
    const int*   ei   = (const int*)d_in[1];   // [2,E] flat: row then col
    const float* ea   = (const float*)d_in[2];
    const int*   bat  = (const int*)d_in[3];
    const float* W1   = (const float*)d_in[4]; // [3,128,1]
    const float* W2   = (const float*)d_in[5]; // [3,128,128]
    const float* W3   = (const float*)d_in[6];
    const float* W4   = (const float*)d_in[7]; // [3,128,1]
    const float* W5   = (const float*)d_in[8]; // [1,256]
    const float* b5   = (const float*)d_in[9];
    const float* W6   = (const float*)d_in[10];
    const float* W7   = (const float*)d_in[11];
    float* out = (float*)d_out;

    const int* row = ei;
    const int* col = ei + N_EDGES;

    // workspace layout (4B elems)
    float* wsf = (float*)d_ws;
    int*   wsi = (int*)d_ws;
    size_t o = 0;
    float* pooled = wsf + o; o += NGRAPH * HID;     // zeroed (atomic targets)
    float* s_g    = wsf + o; o += NGRAPH;           // zeroed
    size_t ztot = o;
    int*   offs   = wsi + o; o += N_NODES + 1;
    float* ea_sum = wsf + o; o += N_NODES;
    int*   gstart = wsi + o; o += NGRAPH + 1;
    int*   btot   = wsi + o; o += NB;
    int*   bbase  = wsi + o; o += NB + 1;
    float* v3     = wsf + o; o += 3 * HID;
    int*   blkh   = wsi + o; o += NB * NBLK;
    o = (o + 1) & ~(size_t)1;
    float2* pxe   = (float2*)(wsi + o); o += 2 * (size_t)N_NODES;
    o = (o + 3) & ~(size_t)3;
    ushort* wpack = (ushort*)(wsi + o); o += 4 * 16384 / 2;
    int*    csr   = wsi + o; o += N_EDGES;
    o = (o + 1) & ~(size_t)1;
    int2*   pea   = (int2*)(wsi + o); o += 2 * (size_t)N_EDGES;
    float2* pxec  = (float2*)(wsi + o); o += 2 * (size_t)N_EDGES;
    o = (o + 1) & ~(size_t)1;
    uint32* embA  = (uint32*)(wsi + o); o += (size_t)N_NODES * 64;  // bf16 [N][128]
    uchar*  emb8  = (uchar*)(wsi + o);  o += (size_t)N_NODES * 32;  // fp8  [N][128]
    uint32* aggB  = (uint32*)(wsi + o); o += (size_t)N_NODES * 64;  // bf16 [N][128]

    const ushort* w2p1 = wpack + 1 * 16384;
    const ushort* w2p2 = wpack + 2 * 16384;
    const ushort* w7p  = wpack + 3 * 16384;

    // 0) zero atomic accumulators + graph boundaries (fused)
    k_init<<<(int)((ztot + 255) / 256), 256, 0, stream>>>((float*)d_ws, (int)ztot, bat, gstart);
    // 1) atomic-free CSR build + CSR-ordered hop-1 payload
    k_p1_hist<<<NBLK, 1024, 0, stream>>>(row, blkh);
    k_p2a<<<NB, NBLK, 0, stream>>>(blkh, btot);
    k_p2b<<<1, 512, 0, stream>>>(btot, bbase);
    k_p3_part<<<NBLK, 1024, 0, stream>>>(row, col, ea, blkh, bbase, pea);
    k_p4a<<<NB, 512, 0, stream>>>(pea, bbase, x, offs, ea_sum, pxe);
    k_p4b<<<NB, 512, 0, stream>>>(pea, bbase, offs, pxe, csr, pxec);
    // 2) weight prep: MFMA B-frag packs + v3
    k_prep<<<(4 * 16384 + 255) / 256, 256, 0, stream>>>(W2, W7, W3, W4, (ushort*)wpack, v3);
    // 3) hop 1: streaming recompute-gather -> aggB ; MFMA gemm -> emb8 (fp8, scale 2^-6)
    k_gather1<<<(N_NODES * 64 + 255) / 256, 256, 0, stream>>>(pxec, offs, W1, v3, aggB);
    k_gemm<false><<<(N_NODES + 63) / 64, 256, 0, stream>>>(
        aggB, w2p1, W1 + 1 * HID, v3 + 1 * HID, x, ea_sum, nullptr, emb8, nullptr, nullptr, nullptr);
    // 4) hop 2: gather emb8 -> aggB ; MFMA gemm + W7 head -> embA, out partial
    k_gather<<<(N_NODES * 64 + 255) / 256, 256, 0, stream>>>(emb8, offs, csr, aggB);
    k_gemm<true><<<(N_NODES + 63) / 64, 256, 0, stream>>>(
        aggB, w2p2, W1 + 2 * HID, v3 + 2 * HID, x, ea_sum, embA, nullptr, w7p, W5, out);
    // 5) graph pooling (parallel, branch-free)
    k_pool2<<<NGRAPH * 16, 256, 0, stream>>>(embA, gstart, pooled);
    // 6) per-graph scalars
    k_graph<<<NGRAPH, 128, 0, stream>>>(pooled, W6, W5, s_g);
    // 7) add graph term + bias
    k_addsg<<<(N_NODES + 255) / 256, 256, 0, stream>>>(out, bat, s_g, b5);
}